// Round 4
// baseline (539.179 us; speedup 1.0000x reference)
//
#include <hip/hip_runtime.h>
#include <hip/hip_bf16.h>
#include <math.h>

#define D_MODEL 1024
#define INTER   1024
#define NEXP    8
#define T_TOK   8192
#define ROWCAP  17408   // 2*T + 8*127 padded up to 128

typedef short  short8 __attribute__((ext_vector_type(8)));
typedef float  f32x4  __attribute__((ext_vector_type(4)));

__device__ __forceinline__ ushort f2bf(float f) {
    uint u = __float_as_uint(f);
    u += 0x7fffu + ((u >> 16) & 1u);      // RNE (inputs finite)
    return (ushort)(u >> 16);
}
__device__ __forceinline__ float bf2f(ushort u) {
    return __uint_as_float((uint)u << 16);
}
__device__ __forceinline__ uint pk2(float lo, float hi) {
    return (uint)f2bf(lo) | ((uint)f2bf(hi) << 16);
}
__device__ __forceinline__ void gll16(const ushort* g, ushort* l) {
    __builtin_amdgcn_global_load_lds(
        (const __attribute__((address_space(1))) unsigned int*)(g),
        (__attribute__((address_space(3))) unsigned int*)(l), 16, 0, 0);
}

// tiled-swizzled LDS/weight image: rows x 64 k bf16; row stride 64 ushort;
// logical 16B chunk c (0..7) of row r sits at image chunk c ^ (r & 7).
#define IDX64(r, c) ((r) * 64 + (((c) ^ ((r) & 7)) * 8))

// ---------------- X fp32 -> bf16 (one-shot; enables gll16 A-staging) -------
__global__ __launch_bounds__(256)
void k_xbf(const float* __restrict__ X, ushort* __restrict__ Xb)
{
    const size_t i = ((size_t)blockIdx.x * 256 + threadIdx.x) * 8;
    float4 a = *(const float4*)(X + i);
    float4 b = *(const float4*)(X + i + 4);
    uint4 o = { pk2(a.x, a.y), pk2(a.z, a.w), pk2(b.x, b.y), pk2(b.z, b.w) };
    *(uint4*)(Xb + i) = o;
}

// ---------------- gate: GW in regs, 8 tokens/wave, butterfly reduce --------
__global__ __launch_bounds__(256)
void k_gate(const float* __restrict__ X, const float* __restrict__ GW,
            int* __restrict__ topk_idx, float* __restrict__ topk_w,
            int* __restrict__ cnt)
{
    __shared__ int lcnt[NEXP];
    const int t = threadIdx.x;
    if (t < NEXP) lcnt[t] = 0;
    const int lane = t & 63, wv = t >> 6;
    float4 gwr[NEXP][4];
#pragma unroll
    for (int e = 0; e < NEXP; ++e)
#pragma unroll
        for (int i = 0; i < 4; ++i)
            gwr[e][i] = *(const float4*)(GW + e * 1024 + i * 256 + lane * 4);
    __syncthreads();
    const int tok0 = blockIdx.x * 32 + wv * 8;
    const bool b0 = lane & 1, b1 = lane & 2, b2 = lane & 4;
    for (int tt = 0; tt < 8; ++tt) {
        const int tok = tok0 + tt;
        const float* xr = X + (size_t)tok * 1024;
        float4 xv[4];
#pragma unroll
        for (int i = 0; i < 4; ++i) xv[i] = *(const float4*)(xr + i * 256 + lane * 4);
        float p[NEXP];
#pragma unroll
        for (int e = 0; e < NEXP; ++e) {
            float s = 0.f;
#pragma unroll
            for (int i = 0; i < 4; ++i)
                s += xv[i].x * gwr[e][i].x + xv[i].y * gwr[e][i].y
                   + xv[i].z * gwr[e][i].z + xv[i].w * gwr[e][i].w;
            p[e] = s;
        }
        float q[4];
#pragma unroll
        for (int j = 0; j < 4; ++j) {
            float send = b0 ? p[j] : p[j + 4];
            float recv = __shfl_xor(send, 1, 64);
            q[j] = (b0 ? p[j + 4] : p[j]) + recv;
        }
        float u2[2];
#pragma unroll
        for (int j = 0; j < 2; ++j) {
            float send = b1 ? q[j] : q[j + 2];
            float recv = __shfl_xor(send, 2, 64);
            u2[j] = (b1 ? q[j + 2] : q[j]) + recv;
        }
        float send = b2 ? u2[0] : u2[1];
        float r = (b2 ? u2[1] : u2[0]) + __shfl_xor(send, 4, 64);
        r += __shfl_xor(r, 8, 64);
        r += __shfl_xor(r, 16, 64);
        r += __shfl_xor(r, 32, 64);
        float sc[NEXP];
#pragma unroll
        for (int e = 0; e < NEXP; ++e)
            sc[e] = __shfl(r, ((e & 1) << 2) | (e & 2) | ((e >> 2) & 1), 64);
        float m = sc[0];
#pragma unroll
        for (int e = 1; e < NEXP; ++e) m = fmaxf(m, sc[e]);
        float ssum = 0.f;
#pragma unroll
        for (int e = 0; e < NEXP; ++e) { sc[e] = __expf(sc[e] - m); ssum += sc[e]; }
        float inv = 1.f / ssum;
#pragma unroll
        for (int e = 0; e < NEXP; ++e) sc[e] *= inv;
        int i0 = 0; float v0 = sc[0];
#pragma unroll
        for (int e = 1; e < NEXP; ++e) if (sc[e] > v0) { v0 = sc[e]; i0 = e; }
        int i1 = -1; float v1 = -1e30f;
#pragma unroll
        for (int e = 0; e < NEXP; ++e) if (e != i0 && sc[e] > v1) { v1 = sc[e]; i1 = e; }
        if (lane == 0) {
            topk_idx[2 * tok]     = i0;
            topk_idx[2 * tok + 1] = i1;
            topk_w[2 * tok]       = v0;
            topk_w[2 * tok + 1]   = v1;
            atomicAdd(&lcnt[i0], 1);
            atomicAdd(&lcnt[i1], 1);
        }
    }
    __syncthreads();
    if (t < NEXP) atomicAdd(&cnt[t], lcnt[t]);
}

// prefix over 128-padded expert segments + 256-row block offsets
__global__ void k_prefix(const int* __restrict__ cnt, int* __restrict__ offs,
                         int* __restrict__ blk)
{
    if (threadIdx.x == 0 && blockIdx.x == 0) {
        int tot = 0, bt = 0;
        for (int e = 0; e < NEXP; ++e) {
            offs[e] = tot;
            blk[e]  = bt;
            int Lp = ((cnt[e] + 127) >> 7) << 7;
            tot += Lp;
            bt  += (Lp + 255) >> 8;
        }
        offs[NEXP] = tot;
        blk[NEXP]  = bt;
    }
}

// scatter with block-aggregated atomics; also records which top-k slot (0/1)
__global__ void k_scatter(const int* __restrict__ topk_idx, const float* __restrict__ topk_w,
                          const int* __restrict__ offs, int* __restrict__ cnt2,
                          int* __restrict__ rowid, float* __restrict__ rowwt,
                          int* __restrict__ rowslot)
{
    __shared__ int loc[NEXP];
    __shared__ int base[NEXP];
    const int t = threadIdx.x;
    if (t < NEXP) loc[t] = 0;
    __syncthreads();
    const int tok = blockIdx.x * 256 + t;
    const int e0 = topk_idx[2 * tok], e1 = topk_idx[2 * tok + 1];
    const int s0 = atomicAdd(&loc[e0], 1);
    const int s1 = atomicAdd(&loc[e1], 1);
    __syncthreads();
    if (t < NEXP) base[t] = atomicAdd(&cnt2[t], loc[t]);
    __syncthreads();
    int p0 = offs[e0] + base[e0] + s0;
    rowid[p0] = tok; rowwt[p0] = topk_w[2 * tok]; rowslot[p0] = 0;
    int p1 = offs[e1] + base[e1] + s1;
    rowid[p1] = tok; rowwt[p1] = topk_w[2 * tok + 1]; rowslot[p1] = 1;
}

// ------- transpose fp32 [K][N] -> tiled swizzled bf16 (128n x 64k tiles) ----
__global__ __launch_bounds__(256)
void k_tw(const float* __restrict__ srcA, ushort* __restrict__ dstA,
          const float* __restrict__ srcB, ushort* __restrict__ dstB, int nA)
{
    __shared__ float tl[64][132];
    int m = blockIdx.y;
    const float* src; ushort* dst;
    if (m < nA) { src = srcA + ((size_t)m << 20); dst = dstA + ((size_t)m << 20); }
    else { m -= nA;  src = srcB + ((size_t)m << 20); dst = dstB + ((size_t)m << 20); }
    const int tile = blockIdx.x;            // nb*16 + kt
    const int nb = tile >> 4, kt = tile & 15;
    const int t = threadIdx.x;
    const int c4 = (t & 31) * 4, kr = t >> 5;
#pragma unroll
    for (int i = 0; i < 8; ++i) {
        const int kl = kr + 8 * i;
        float4 v = *(const float4*)(src + (size_t)(kt * 64 + kl) * 1024 + nb * 128 + c4);
        tl[kl][c4 + 0] = v.x; tl[kl][c4 + 1] = v.y;
        tl[kl][c4 + 2] = v.z; tl[kl][c4 + 3] = v.w;
    }
    __syncthreads();
    const int nl = t >> 1, h = t & 1;
    ushort* drow = dst + (size_t)tile * 8192 + nl * 64;
#pragma unroll
    for (int w = 0; w < 4; ++w) {
        const int cimg = h * 4 + w;
        const int cl = cimg ^ (nl & 7);
        float f[8];
#pragma unroll
        for (int j = 0; j < 8; ++j) f[j] = tl[cl * 8 + j][nl];
        uint4 o = { pk2(f[0], f[1]), pk2(f[2], f[3]), pk2(f[4], f[5]), pk2(f[6], f[7]) };
        *(uint4*)(drow + cimg * 8) = o;
    }
}

// ---------------- H = silu(X@W1+b1) * (X@W3+b3), BM=256, 8 waves, dbuf ------
// 512 threads, BN=128 (both B1,B3), BK=64. 128 KB LDS (2x {A 32K, B1 16K, B3 16K}).
// One barrier per K-step; next tile's 8 gll16/thread fly under 64 MFMA/wave.
template <bool ROUTED>
__global__ __launch_bounds__(512, 2)
void k_h(const ushort* __restrict__ Xb,
         const ushort* __restrict__ W1t, const float* __restrict__ B1,
         const ushort* __restrict__ W3t, const float* __restrict__ B3,
         ushort* __restrict__ Hb,
         const int* __restrict__ rowid, const int* __restrict__ offs,
         const int* __restrict__ blk, const int* __restrict__ cnt)
{
    __shared__ __align__(16) ushort As [2][16384];
    __shared__ __align__(16) ushort B1s[2][8192];
    __shared__ __align__(16) ushort B3s[2][8192];

    const int nbx = blockIdx.x;             // 0..7: 128-col block
    int row0, rstart = 0, rcount = T_TOK, Lpad = T_TOK;
    const ushort* w1 = W1t; const ushort* w3 = W3t;
    if constexpr (ROUTED) {
        const int by = blockIdx.y;
        if (by >= blk[NEXP]) return;
        int e = 0;
        while (blk[e + 1] <= by) ++e;
        rstart = offs[e]; rcount = cnt[e];
        Lpad = ((rcount + 127) >> 7) << 7;
        row0 = rstart + ((by - blk[e]) << 8);
        w1 += (size_t)e << 20; B1 += e * INTER;
        w3 += (size_t)e << 20; B3 += e * INTER;
    } else {
        row0 = blockIdx.y << 8;
    }
    const int t = threadIdx.x;

    // B sources: 2 chunks each of B1,B3 per thread (1024 chunks / 512 thr)
    const ushort* g1 = w1 + (size_t)(nbx * 16) * 8192;
    const ushort* g3 = w3 + (size_t)(nbx * 16) * 8192;

    // A sources: 4 rows per thread; inverse-swizzled global, linear LDS dest
    const int sub = t >> 3, ci = t & 7;
    const ushort* asrc[4];
#pragma unroll
    for (int c = 0; c < 4; ++c) {
        const int r = c * 64 + sub;
        int tok;
        if constexpr (ROUTED) {
            bool v = (row0 + r - rstart) < rcount;
            tok = v ? rowid[row0 + r] : 0;
        } else {
            tok = row0 + r;
        }
        asrc[c] = Xb + (size_t)tok * 1024 + (size_t)((ci ^ (sub & 7)) * 8);
    }

    // fragment offsets (ks=1 offset = ks=0 offset ^ 32)
    const int lane = t & 63, wid = t >> 6;
    const int wm = wid & 3, wn = wid >> 2;    // rows wm*64, cols wn*64
    const int m16 = lane & 15, g = lane >> 4;
    int offA[4], offB[4];
#pragma unroll
    for (int i = 0; i < 4; ++i) {
        offA[i] = IDX64(wm * 64 + i * 16 + m16, g);
        offB[i] = IDX64(wn * 64 + i * 16 + m16, g);
    }

    const f32x4 zf = {0.f, 0.f, 0.f, 0.f};
    f32x4 acc1[4][4], acc3[4][4];
#pragma unroll
    for (int i = 0; i < 4; ++i)
#pragma unroll
        for (int j = 0; j < 4; ++j) { acc1[i][j] = zf; acc3[i][j] = zf; }

    // prologue: stage K-tile 0 into buffer 0
#pragma unroll
    for (int c = 0; c < 4; ++c)
        gll16(asrc[c], &As[0][(t + 512 * c) * 8]);
#pragma unroll
    for (int c = 0; c < 2; ++c) {
        gll16(g1 + (t + 512 * c) * 8, &B1s[0][(t + 512 * c) * 8]);
        gll16(g3 + (t + 512 * c) * 8, &B3s[0][(t + 512 * c) * 8]);
    }

    int cur = 0;
    for (int kt = 0; kt < 16; ++kt) {
        __syncthreads();   // drains vmcnt: buf[cur] ready; all prev LDS reads done
        if (kt < 15) {
#pragma unroll
            for (int c = 0; c < 4; ++c)
                gll16(asrc[c] + (kt + 1) * 64, &As[cur ^ 1][(t + 512 * c) * 8]);
#pragma unroll
            for (int c = 0; c < 2; ++c) {
                gll16(g1 + (size_t)(kt + 1) * 8192 + (t + 512 * c) * 8,
                      &B1s[cur ^ 1][(t + 512 * c) * 8]);
                gll16(g3 + (size_t)(kt + 1) * 8192 + (t + 512 * c) * 8,
                      &B3s[cur ^ 1][(t + 512 * c) * 8]);
            }
        }
#pragma unroll
        for (int ks = 0; ks < 2; ++ks) {
            const int x = ks * 32;
            short8 af[4], b1f[4], b3f[4];
#pragma unroll
            for (int i = 0; i < 4; ++i) {
                af[i]  = *(const short8*)&As [cur][offA[i] ^ x];
                b1f[i] = *(const short8*)&B1s[cur][offB[i] ^ x];
                b3f[i] = *(const short8*)&B3s[cur][offB[i] ^ x];
            }
#pragma unroll
            for (int i = 0; i < 4; ++i)
#pragma unroll
                for (int j = 0; j < 4; ++j) {
                    acc1[i][j] = __builtin_amdgcn_mfma_f32_16x16x32_bf16(af[i], b1f[j], acc1[i][j], 0, 0, 0);
                    acc3[i][j] = __builtin_amdgcn_mfma_f32_16x16x32_bf16(af[i], b3f[j], acc3[i][j], 0, 0, 0);
                }
        }
        cur ^= 1;
    }

    // epilogue: SwiGLU; mask rows beyond this expert's padded segment
#pragma unroll
    for (int j = 0; j < 4; ++j) {
        const int gcol = nbx * 128 + wn * 64 + j * 16 + m16;
        const float bb1 = B1[gcol];
        const float bb3 = B3[gcol];
#pragma unroll
        for (int i = 0; i < 4; ++i) {
            const int growb = row0 + wm * 64 + i * 16 + g * 4;
#pragma unroll
            for (int r = 0; r < 4; ++r) {
                const int grow = growb + r;
                if ((grow - rstart) < Lpad) {
                    float x1 = acc1[i][j][r] + bb1;
                    float x3 = acc3[i][j][r] + bb3;
                    float h = x1 / (1.f + __expf(-x1)) * x3;
                    Hb[(size_t)grow * INTER + gcol] = f2bf(h);
                }
            }
        }
    }
}

// ---------------- out = H@W2 + b2, BM=256, BN=256, 8 waves, dbuf -----------
//   MODE 0: shared expert  -> plain store to out
//   MODE 2: routed, race-free weighted bf16 store into Y[slot][tok][col]
template <int MODE>
__global__ __launch_bounds__(512, 2)
void k_out(const ushort* __restrict__ Hin,
           const ushort* __restrict__ W2t, const float* __restrict__ B2,
           float* __restrict__ out,
           const int* __restrict__ rowid, const int* __restrict__ offs,
           const int* __restrict__ blk, const int* __restrict__ cnt,
           const float* __restrict__ rowwt, const int* __restrict__ rowslot,
           ushort* __restrict__ Yb)
{
    __shared__ __align__(16) ushort As[2][16384];
    __shared__ __align__(16) ushort Bs[2][16384];

    const int nbx = blockIdx.x;             // 0..3: 256-col block
    int row0, rstart = 0, rcount = T_TOK;
    const ushort* w2 = W2t;
    if constexpr (MODE != 0) {
        const int by = blockIdx.y;
        if (by >= blk[NEXP]) return;
        int e = 0;
        while (blk[e + 1] <= by) ++e;
        rstart = offs[e]; rcount = cnt[e];
        row0 = rstart + ((by - blk[e]) << 8);
        w2 += (size_t)e << 20; B2 += e * D_MODEL;
    } else {
        row0 = blockIdx.y << 8;
    }
    const int t = threadIdx.x;

    // A sources (4 rows/thread); B sources (4 chunks/thread over 2 sub-images)
    const int sub = t >> 3, ci = t & 7;
    const ushort* asrc[4];
    const ushort* bsrc[4];
#pragma unroll
    for (int c = 0; c < 4; ++c) {
        const int r = c * 64 + sub;
        asrc[c] = Hin + (size_t)(row0 + r) * 1024 + (size_t)((ci ^ (sub & 7)) * 8);
        const int cc = t + 512 * c;
        const int s = cc >> 10;
        bsrc[c] = w2 + (size_t)((nbx * 2 + s) * 16) * 8192 + (size_t)(cc & 1023) * 8;
    }

    const int lane = t & 63, wid = t >> 6;
    const int wm = wid >> 2, wn = wid & 3;  // rows wm*128, cols wn*64
    const int m16 = lane & 15, g = lane >> 4;
    int offA[8], offB[4];
#pragma unroll
    for (int i = 0; i < 8; ++i)
        offA[i] = IDX64(wm * 128 + i * 16 + m16, g);
#pragma unroll
    for (int j = 0; j < 4; ++j) {
        const int col = wn * 64 + j * 16 + m16;
        offB[j] = ((col >> 7) * 8192) + IDX64(col & 127, g);
    }

    const f32x4 zf = {0.f, 0.f, 0.f, 0.f};
    f32x4 acc[8][4];
#pragma unroll
    for (int i = 0; i < 8; ++i)
#pragma unroll
        for (int j = 0; j < 4; ++j) acc[i][j] = zf;

    // prologue: stage K-tile 0
#pragma unroll
    for (int c = 0; c < 4; ++c) {
        gll16(asrc[c], &As[0][(t + 512 * c) * 8]);
        gll16(bsrc[c], &Bs[0][(t + 512 * c) * 8]);
    }

    int cur = 0;
    for (int kt = 0; kt < 16; ++kt) {
        __syncthreads();
        if (kt < 15) {
#pragma unroll
            for (int c = 0; c < 4; ++c) {
                gll16(asrc[c] + (kt + 1) * 64,  &As[cur ^ 1][(t + 512 * c) * 8]);
                gll16(bsrc[c] + (size_t)(kt + 1) * 8192, &Bs[cur ^ 1][(t + 512 * c) * 8]);
            }
        }
#pragma unroll
        for (int ks = 0; ks < 2; ++ks) {
            const int x = ks * 32;
            short8 af[8], bf[4];
#pragma unroll
            for (int i = 0; i < 8; ++i) af[i] = *(const short8*)&As[cur][offA[i] ^ x];
#pragma unroll
            for (int j = 0; j < 4; ++j) bf[j] = *(const short8*)&Bs[cur][offB[j] ^ x];
#pragma unroll
            for (int i = 0; i < 8; ++i)
#pragma unroll
                for (int j = 0; j < 4; ++j)
                    acc[i][j] = __builtin_amdgcn_mfma_f32_16x16x32_bf16(af[i], bf[j], acc[i][j], 0, 0, 0);
        }
        cur ^= 1;
    }

#pragma unroll
    for (int i = 0; i < 8; ++i) {
#pragma unroll
        for (int r = 0; r < 4; ++r) {
            const int grow = row0 + wm * 128 + i * 16 + g * 4 + r;
            if constexpr (MODE == 0) {
#pragma unroll
                for (int j = 0; j < 4; ++j) {
                    const int gcol = nbx * 256 + wn * 64 + j * 16 + m16;
                    out[(size_t)grow * D_MODEL + gcol] = acc[i][j][r] + B2[gcol];
                }
            } else {
                const bool valid = (grow - rstart) < rcount;
                if (!valid) continue;
                const int tok = rowid[grow];
                const float wt = rowwt[grow];
                const int sk = rowslot[grow];
                ushort* yr = Yb + (((size_t)sk * T_TOK + tok) << 10);
#pragma unroll
                for (int j = 0; j < 4; ++j) {
                    const int gcol = nbx * 256 + wn * 64 + j * 16 + m16;
                    yr[gcol] = f2bf(wt * (acc[i][j][r] + B2[gcol]));
                }
            }
        }
    }
}

// ---------------- out[tok] += Y[0][tok] + Y[1][tok] (dense, coalesced) -----
__global__ __launch_bounds__(256)
void k_combine(float* __restrict__ out, const ushort* __restrict__ Yb)
{
    const int row = blockIdx.x;            // 0..8191
    const int c = threadIdx.x * 4;
    float4 o = *(const float4*)(out + (size_t)row * 1024 + c);
    ushort4 y0 = *(const ushort4*)(Yb + (size_t)row * 1024 + c);
    ushort4 y1 = *(const ushort4*)(Yb + ((size_t)(T_TOK + row)) * 1024 + c);
    o.x += bf2f(y0.x) + bf2f(y1.x);
    o.y += bf2f(y0.y) + bf2f(y1.y);
    o.z += bf2f(y0.z) + bf2f(y1.z);
    o.w += bf2f(y0.w) + bf2f(y1.w);
    *(float4*)(out + (size_t)row * 1024 + c) = o;
}

// ---------------- launcher ----------------
// ws map (bytes) — unchanged from proven rounds 1-3 (ws_size >= 86,507,520):
//   [0,32)   cnt    [64,96) cnt2   [128,164) offs   [192,228) blk
//   [256,65792) topk_idx  [65792,131328) topk_w
//   [131328,200960) rowid [200960,270592) rowwt [270592,340224) rowslot
//   [524288, 36175872)  Hb  (ROWCAP*2048)
//   [36175872, 69730304) WA..WB (32 MB): w1t/w3t images; later Yb
//   [69730304, 86507520) WC (16 MB): Xbf until routed k_h done, then w2t
extern "C" void kernel_launch(void* const* d_in, const int* in_sizes, int n_in,
                              void* d_out, int out_size, void* d_ws, size_t ws_size,
                              hipStream_t stream)
{
    const float* x   = (const float*)d_in[0];
    const float* gw  = (const float*)d_in[1];
    const float* w1  = (const float*)d_in[2];
    const float* b1  = (const float*)d_in[3];
    const float* w2  = (const float*)d_in[4];
    const float* b2  = (const float*)d_in[5];
    const float* w3  = (const float*)d_in[6];
    const float* b3  = (const float*)d_in[7];
    const float* sw1 = (const float*)d_in[8];
    const float* sb1 = (const float*)d_in[9];
    const float* sw2 = (const float*)d_in[10];
    const float* sb2 = (const float*)d_in[11];
    const float* sw3 = (const float*)d_in[12];
    const float* sb3 = (const float*)d_in[13];
    float* out = (float*)d_out;

    char* ws = (char*)d_ws;
    int*   cnt      = (int*)(ws);
    int*   cnt2     = (int*)(ws + 64);
    int*   offs     = (int*)(ws + 128);
    int*   blk      = (int*)(ws + 192);
    int*   topk_idx = (int*)(ws + 256);
    float* topk_w   = (float*)(ws + 256 + 65536);
    int*   rowid    = (int*)(ws + 256 + 131072);
    float* rowwt    = (float*)(ws + 256 + 131072 + ROWCAP * 4);
    int*   rowslot  = (int*)(ws + 256 + 131072 + ROWCAP * 8);
    ushort* Hb = (ushort*)(ws + 524288);
    ushort* WA = (ushort*)(ws + 524288 + (size_t)ROWCAP * 2048); // 36,175,872
    ushort* WB = WA + (8u << 20);                                // +16 MB
    ushort* WC = WB + (8u << 20);                                // +16 MB

    ushort* sw1t = WB;
    ushort* sw3t = WB + (1 << 20);
    ushort* sw2t = WA;
    ushort* w1t  = WA;
    ushort* w3t  = WB;
    ushort* w2t  = WC;   // after Xbf dead
    ushort* Xbf  = WC;   // alive until routed k_h done
    ushort* Yb   = WA;   // 32 MB spanning WA+WB; w1t/w3t dead by routed k_out

    hipMemsetAsync(ws, 0, 256, stream);

    k_gate<<<256, 256, 0, stream>>>(x, gw, topk_idx, topk_w, cnt);
    k_prefix<<<1, 64, 0, stream>>>(cnt, offs, blk);
    k_scatter<<<32, 256, 0, stream>>>(topk_idx, topk_w, offs, cnt2, rowid, rowwt, rowslot);
    k_xbf<<<4096, 256, 0, stream>>>(x, Xbf);

    // shared expert
    k_tw<<<dim3(128, 2), 256, 0, stream>>>(sw1, sw1t, sw3, sw3t, 1);
    k_h<false><<<dim3(8, 32), 512, 0, stream>>>(Xbf, sw1t, sb1, sw3t, sb3, Hb,
                                                nullptr, nullptr, nullptr, nullptr);
    k_tw<<<dim3(128, 1), 256, 0, stream>>>(sw2, sw2t, sw2, sw2t, 1);
    k_out<0><<<dim3(4, 32), 512, 0, stream>>>(Hb, sw2t, sb2, out,
                                              nullptr, nullptr, nullptr, nullptr,
                                              nullptr, nullptr, nullptr);

    // routed experts
    k_tw<<<dim3(128, 16), 256, 0, stream>>>(w1, w1t, w3, w3t, 8);  // overwrites sw2t (dead)
    k_h<true><<<dim3(8, 72), 512, 0, stream>>>(Xbf, w1t, b1, w3t, b3, Hb,
                                               rowid, offs, blk, cnt);
    k_tw<<<dim3(128, 8), 256, 0, stream>>>(w2, w2t, w2, w2t, 8);   // overwrites Xbf (dead)
    k_out<2><<<dim3(4, 72), 512, 0, stream>>>(Hb, w2t, b2, out,
                                              rowid, offs, blk, cnt,
                                              rowwt, rowslot, Yb);
    k_combine<<<T_TOK, 256, 0, stream>>>(out, Yb);
}

// Round 5
// 519.548 us; speedup vs baseline: 1.0378x; 1.0378x over previous
//
#include <hip/hip_runtime.h>
#include <hip/hip_bf16.h>
#include <math.h>

#define D_MODEL 1024
#define INTER   1024
#define NEXP    8
#define T_TOK   8192
#define ROWCAP  17408   // 2*T + 8*127 padded up to 128

typedef short  short8 __attribute__((ext_vector_type(8)));
typedef float  f32x4  __attribute__((ext_vector_type(4)));

__device__ __forceinline__ ushort f2bf(float f) {
    uint u = __float_as_uint(f);
    u += 0x7fffu + ((u >> 16) & 1u);      // RNE (inputs finite)
    return (ushort)(u >> 16);
}
__device__ __forceinline__ float bf2f(ushort u) {
    return __uint_as_float((uint)u << 16);
}
__device__ __forceinline__ uint pk2(float lo, float hi) {
    return (uint)f2bf(lo) | ((uint)f2bf(hi) << 16);
}
__device__ __forceinline__ void gll16(const ushort* g, ushort* l) {
    __builtin_amdgcn_global_load_lds(
        (const __attribute__((address_space(1))) unsigned int*)(g),
        (__attribute__((address_space(3))) unsigned int*)(l), 16, 0, 0);
}

// tiled-swizzled LDS/weight image: rows x 64 k bf16; row stride 64 ushort;
// logical 16B chunk c (0..7) of row r sits at image chunk c ^ (r & 7).
#define IDX64(r, c) ((r) * 64 + (((c) ^ ((r) & 7)) * 8))

// ---------------- X fp32 -> bf16 (one-shot; enables gll16 A-staging) -------
__global__ __launch_bounds__(256)
void k_xbf(const float* __restrict__ X, ushort* __restrict__ Xb)
{
    const size_t i = ((size_t)blockIdx.x * 256 + threadIdx.x) * 8;
    float4 a = *(const float4*)(X + i);
    float4 b = *(const float4*)(X + i + 4);
    uint4 o = { pk2(a.x, a.y), pk2(a.z, a.w), pk2(b.x, b.y), pk2(b.z, b.w) };
    *(uint4*)(Xb + i) = o;
}

// ---------------- gate: GW in regs, 8 tokens/wave, butterfly reduce --------
__global__ __launch_bounds__(256)
void k_gate(const float* __restrict__ X, const float* __restrict__ GW,
            int* __restrict__ topk_idx, float* __restrict__ topk_w,
            int* __restrict__ cnt)
{
    __shared__ int lcnt[NEXP];
    const int t = threadIdx.x;
    if (t < NEXP) lcnt[t] = 0;
    const int lane = t & 63, wv = t >> 6;
    float4 gwr[NEXP][4];
#pragma unroll
    for (int e = 0; e < NEXP; ++e)
#pragma unroll
        for (int i = 0; i < 4; ++i)
            gwr[e][i] = *(const float4*)(GW + e * 1024 + i * 256 + lane * 4);
    __syncthreads();
    const int tok0 = blockIdx.x * 32 + wv * 8;
    const bool b0 = lane & 1, b1 = lane & 2, b2 = lane & 4;
    for (int tt = 0; tt < 8; ++tt) {
        const int tok = tok0 + tt;
        const float* xr = X + (size_t)tok * 1024;
        float4 xv[4];
#pragma unroll
        for (int i = 0; i < 4; ++i) xv[i] = *(const float4*)(xr + i * 256 + lane * 4);
        float p[NEXP];
#pragma unroll
        for (int e = 0; e < NEXP; ++e) {
            float s = 0.f;
#pragma unroll
            for (int i = 0; i < 4; ++i)
                s += xv[i].x * gwr[e][i].x + xv[i].y * gwr[e][i].y
                   + xv[i].z * gwr[e][i].z + xv[i].w * gwr[e][i].w;
            p[e] = s;
        }
        float q[4];
#pragma unroll
        for (int j = 0; j < 4; ++j) {
            float send = b0 ? p[j] : p[j + 4];
            float recv = __shfl_xor(send, 1, 64);
            q[j] = (b0 ? p[j + 4] : p[j]) + recv;
        }
        float u2[2];
#pragma unroll
        for (int j = 0; j < 2; ++j) {
            float send = b1 ? q[j] : q[j + 2];
            float recv = __shfl_xor(send, 2, 64);
            u2[j] = (b1 ? q[j + 2] : q[j]) + recv;
        }
        float send = b2 ? u2[0] : u2[1];
        float r = (b2 ? u2[1] : u2[0]) + __shfl_xor(send, 4, 64);
        r += __shfl_xor(r, 8, 64);
        r += __shfl_xor(r, 16, 64);
        r += __shfl_xor(r, 32, 64);
        float sc[NEXP];
#pragma unroll
        for (int e = 0; e < NEXP; ++e)
            sc[e] = __shfl(r, ((e & 1) << 2) | (e & 2) | ((e >> 2) & 1), 64);
        float m = sc[0];
#pragma unroll
        for (int e = 1; e < NEXP; ++e) m = fmaxf(m, sc[e]);
        float ssum = 0.f;
#pragma unroll
        for (int e = 0; e < NEXP; ++e) { sc[e] = __expf(sc[e] - m); ssum += sc[e]; }
        float inv = 1.f / ssum;
#pragma unroll
        for (int e = 0; e < NEXP; ++e) sc[e] *= inv;
        int i0 = 0; float v0 = sc[0];
#pragma unroll
        for (int e = 1; e < NEXP; ++e) if (sc[e] > v0) { v0 = sc[e]; i0 = e; }
        int i1 = -1; float v1 = -1e30f;
#pragma unroll
        for (int e = 0; e < NEXP; ++e) if (e != i0 && sc[e] > v1) { v1 = sc[e]; i1 = e; }
        if (lane == 0) {
            topk_idx[2 * tok]     = i0;
            topk_idx[2 * tok + 1] = i1;
            topk_w[2 * tok]       = v0;
            topk_w[2 * tok + 1]   = v1;
            atomicAdd(&lcnt[i0], 1);
            atomicAdd(&lcnt[i1], 1);
        }
    }
    __syncthreads();
    if (t < NEXP) atomicAdd(&cnt[t], lcnt[t]);
}

// prefix over 128-padded expert segments + 256-row block offsets
__global__ void k_prefix(const int* __restrict__ cnt, int* __restrict__ offs,
                         int* __restrict__ blk)
{
    if (threadIdx.x == 0 && blockIdx.x == 0) {
        int tot = 0, bt = 0;
        for (int e = 0; e < NEXP; ++e) {
            offs[e] = tot;
            blk[e]  = bt;
            int Lp = ((cnt[e] + 127) >> 7) << 7;
            tot += Lp;
            bt  += (Lp + 255) >> 8;
        }
        offs[NEXP] = tot;
        blk[NEXP]  = bt;
    }
}

// scatter with block-aggregated atomics; also records which top-k slot (0/1)
__global__ void k_scatter(const int* __restrict__ topk_idx, const float* __restrict__ topk_w,
                          const int* __restrict__ offs, int* __restrict__ cnt2,
                          int* __restrict__ rowid, float* __restrict__ rowwt,
                          int* __restrict__ rowslot)
{
    __shared__ int loc[NEXP];
    __shared__ int base[NEXP];
    const int t = threadIdx.x;
    if (t < NEXP) loc[t] = 0;
    __syncthreads();
    const int tok = blockIdx.x * 256 + t;
    const int e0 = topk_idx[2 * tok], e1 = topk_idx[2 * tok + 1];
    const int s0 = atomicAdd(&loc[e0], 1);
    const int s1 = atomicAdd(&loc[e1], 1);
    __syncthreads();
    if (t < NEXP) base[t] = atomicAdd(&cnt2[t], loc[t]);
    __syncthreads();
    int p0 = offs[e0] + base[e0] + s0;
    rowid[p0] = tok; rowwt[p0] = topk_w[2 * tok]; rowslot[p0] = 0;
    int p1 = offs[e1] + base[e1] + s1;
    rowid[p1] = tok; rowwt[p1] = topk_w[2 * tok + 1]; rowslot[p1] = 1;
}

// ------- transpose fp32 [K][N] -> tiled swizzled bf16 (128n x 64k tiles) ----
__global__ __launch_bounds__(256)
void k_tw(const float* __restrict__ srcA, ushort* __restrict__ dstA,
          const float* __restrict__ srcB, ushort* __restrict__ dstB, int nA)
{
    __shared__ float tl[64][132];
    int m = blockIdx.y;
    const float* src; ushort* dst;
    if (m < nA) { src = srcA + ((size_t)m << 20); dst = dstA + ((size_t)m << 20); }
    else { m -= nA;  src = srcB + ((size_t)m << 20); dst = dstB + ((size_t)m << 20); }
    const int tile = blockIdx.x;            // nb*16 + kt
    const int nb = tile >> 4, kt = tile & 15;
    const int t = threadIdx.x;
    const int c4 = (t & 31) * 4, kr = t >> 5;
#pragma unroll
    for (int i = 0; i < 8; ++i) {
        const int kl = kr + 8 * i;
        float4 v = *(const float4*)(src + (size_t)(kt * 64 + kl) * 1024 + nb * 128 + c4);
        tl[kl][c4 + 0] = v.x; tl[kl][c4 + 1] = v.y;
        tl[kl][c4 + 2] = v.z; tl[kl][c4 + 3] = v.w;
    }
    __syncthreads();
    const int nl = t >> 1, h = t & 1;
    ushort* drow = dst + (size_t)tile * 8192 + nl * 64;
#pragma unroll
    for (int w = 0; w < 4; ++w) {
        const int cimg = h * 4 + w;
        const int cl = cimg ^ (nl & 7);
        float f[8];
#pragma unroll
        for (int j = 0; j < 8; ++j) f[j] = tl[cl * 8 + j][nl];
        uint4 o = { pk2(f[0], f[1]), pk2(f[2], f[3]), pk2(f[4], f[5]), pk2(f[6], f[7]) };
        *(uint4*)(drow + cimg * 8) = o;
    }
}

// ---------------- H = silu(X@W1+b1) * (X@W3+b3), BM=256, 8 waves -----------
// Counted-vmcnt pipeline (T3+T4): depth-2 prefetch, raw s_barrier, vmcnt(8)
// in steady state (never 0 until the last tile). 8 loads/thread per K-tile.
template <bool ROUTED>
__global__ __launch_bounds__(512, 2)
void k_h(const ushort* __restrict__ Xb,
         const ushort* __restrict__ W1t, const float* __restrict__ B1,
         const ushort* __restrict__ W3t, const float* __restrict__ B3,
         ushort* __restrict__ Hb,
         const int* __restrict__ rowid, const int* __restrict__ offs,
         const int* __restrict__ blk, const int* __restrict__ cnt)
{
    __shared__ __align__(16) ushort As [2][16384];
    __shared__ __align__(16) ushort B1s[2][8192];
    __shared__ __align__(16) ushort B3s[2][8192];

    const int nbx = blockIdx.x;             // 0..7: 128-col block
    int row0, rstart = 0, rcount = T_TOK, Lpad = T_TOK;
    const ushort* w1 = W1t; const ushort* w3 = W3t;
    if constexpr (ROUTED) {
        const int by = blockIdx.y;
        if (by >= blk[NEXP]) return;
        int e = 0;
        while (blk[e + 1] <= by) ++e;
        rstart = offs[e]; rcount = cnt[e];
        Lpad = ((rcount + 127) >> 7) << 7;
        row0 = rstart + ((by - blk[e]) << 8);
        w1 += (size_t)e << 20; B1 += e * INTER;
        w3 += (size_t)e << 20; B3 += e * INTER;
    } else {
        row0 = blockIdx.y << 8;
    }
    const int t = threadIdx.x;

    const ushort* g1 = w1 + (size_t)(nbx * 16) * 8192;
    const ushort* g3 = w3 + (size_t)(nbx * 16) * 8192;

    // A sources: 4 rows per thread; inverse-swizzled global, linear LDS dest
    const int sub = t >> 3, ci = t & 7;
    const ushort* asrc[4];
#pragma unroll
    for (int c = 0; c < 4; ++c) {
        const int r = c * 64 + sub;
        int tok;
        if constexpr (ROUTED) {
            bool v = (row0 + r - rstart) < rcount;
            tok = v ? rowid[row0 + r] : 0;
        } else {
            tok = row0 + r;
        }
        asrc[c] = Xb + (size_t)tok * 1024 + (size_t)((ci ^ (sub & 7)) * 8);
    }

    // exactly 8 gll16 per thread per K-tile (vmcnt accounting depends on it)
    auto stage = [&](int KT, int BUF) {
#pragma unroll
        for (int c = 0; c < 4; ++c)
            gll16(asrc[c] + KT * 64, &As[BUF][(t + 512 * c) * 8]);
#pragma unroll
        for (int c = 0; c < 2; ++c) {
            gll16(g1 + (size_t)KT * 8192 + (t + 512 * c) * 8, &B1s[BUF][(t + 512 * c) * 8]);
            gll16(g3 + (size_t)KT * 8192 + (t + 512 * c) * 8, &B3s[BUF][(t + 512 * c) * 8]);
        }
    };

    // fragment offsets (ks=1 offset = ks=0 offset ^ 32)
    const int lane = t & 63, wid = t >> 6;
    const int wm = wid & 3, wn = wid >> 2;    // rows wm*64, cols wn*64
    const int m16 = lane & 15, g = lane >> 4;
    int offA[4], offB[4];
#pragma unroll
    for (int i = 0; i < 4; ++i) {
        offA[i] = IDX64(wm * 64 + i * 16 + m16, g);
        offB[i] = IDX64(wn * 64 + i * 16 + m16, g);
    }

    const f32x4 zf = {0.f, 0.f, 0.f, 0.f};
    f32x4 acc1[4][4], acc3[4][4];
#pragma unroll
    for (int i = 0; i < 4; ++i)
#pragma unroll
        for (int j = 0; j < 4; ++j) { acc1[i][j] = zf; acc3[i][j] = zf; }

    stage(0, 0);
    stage(1, 1);

    for (int kt = 0; kt < 16; ++kt) {
        if (kt < 15) { asm volatile("s_waitcnt vmcnt(8)" ::: "memory"); }
        else         { asm volatile("s_waitcnt vmcnt(0)" ::: "memory"); }
        __builtin_amdgcn_s_barrier();       // tile kt resident in buf[kt&1]
        const int cur = kt & 1;
        __builtin_amdgcn_s_setprio(1);
#pragma unroll
        for (int ks = 0; ks < 2; ++ks) {
            const int x = ks * 32;
            short8 af[4], b1f[4], b3f[4];
#pragma unroll
            for (int i = 0; i < 4; ++i) {
                af[i]  = *(const short8*)&As [cur][offA[i] ^ x];
                b1f[i] = *(const short8*)&B1s[cur][offB[i] ^ x];
                b3f[i] = *(const short8*)&B3s[cur][offB[i] ^ x];
            }
#pragma unroll
            for (int i = 0; i < 4; ++i)
#pragma unroll
                for (int j = 0; j < 4; ++j) {
                    acc1[i][j] = __builtin_amdgcn_mfma_f32_16x16x32_bf16(af[i], b1f[j], acc1[i][j], 0, 0, 0);
                    acc3[i][j] = __builtin_amdgcn_mfma_f32_16x16x32_bf16(af[i], b3f[j], acc3[i][j], 0, 0, 0);
                }
        }
        __builtin_amdgcn_s_setprio(0);
        if (kt < 14) {
            __builtin_amdgcn_s_barrier();   // all waves done reading buf[cur]
            asm volatile("" ::: "memory");
            stage(kt + 2, cur);             // loads fly across next barriers
        }
    }

    // epilogue: SwiGLU; mask rows beyond this expert's padded segment
#pragma unroll
    for (int j = 0; j < 4; ++j) {
        const int gcol = nbx * 128 + wn * 64 + j * 16 + m16;
        const float bb1 = B1[gcol];
        const float bb3 = B3[gcol];
#pragma unroll
        for (int i = 0; i < 4; ++i) {
            const int growb = row0 + wm * 64 + i * 16 + g * 4;
#pragma unroll
            for (int r = 0; r < 4; ++r) {
                const int grow = growb + r;
                if ((grow - rstart) < Lpad) {
                    float x1 = acc1[i][j][r] + bb1;
                    float x3 = acc3[i][j][r] + bb3;
                    float h = x1 / (1.f + __expf(-x1)) * x3;
                    Hb[(size_t)grow * INTER + gcol] = f2bf(h);
                }
            }
        }
    }
}

// ---------------- out = H@W2 + b2, BM=256, BN=256, 8 waves -----------------
//   MODE 0: shared expert  -> plain store to out
//   MODE 2: routed, race-free weighted bf16 store into Y[slot][tok][col]
// Same counted-vmcnt depth-2 pipeline; 8 loads/thread per K-tile.
template <int MODE>
__global__ __launch_bounds__(512, 2)
void k_out(const ushort* __restrict__ Hin,
           const ushort* __restrict__ W2t, const float* __restrict__ B2,
           float* __restrict__ out,
           const int* __restrict__ rowid, const int* __restrict__ offs,
           const int* __restrict__ blk, const int* __restrict__ cnt,
           const float* __restrict__ rowwt, const int* __restrict__ rowslot,
           ushort* __restrict__ Yb)
{
    __shared__ __align__(16) ushort As[2][16384];
    __shared__ __align__(16) ushort Bs[2][16384];

    const int nbx = blockIdx.x;             // 0..3: 256-col block
    int row0, rstart = 0, rcount = T_TOK;
    const ushort* w2 = W2t;
    if constexpr (MODE != 0) {
        const int by = blockIdx.y;
        if (by >= blk[NEXP]) return;
        int e = 0;
        while (blk[e + 1] <= by) ++e;
        rstart = offs[e]; rcount = cnt[e];
        row0 = rstart + ((by - blk[e]) << 8);
        w2 += (size_t)e << 20; B2 += e * D_MODEL;
    } else {
        row0 = blockIdx.y << 8;
    }
    const int t = threadIdx.x;

    // A sources (4 rows/thread); B sources (4 chunks/thread over 2 sub-images)
    const int sub = t >> 3, ci = t & 7;
    const ushort* asrc[4];
    const ushort* bsrc[4];
#pragma unroll
    for (int c = 0; c < 4; ++c) {
        const int r = c * 64 + sub;
        asrc[c] = Hin + (size_t)(row0 + r) * 1024 + (size_t)((ci ^ (sub & 7)) * 8);
        const int cc = t + 512 * c;
        const int s = cc >> 10;
        bsrc[c] = w2 + (size_t)((nbx * 2 + s) * 16) * 8192 + (size_t)(cc & 1023) * 8;
    }

    auto stage = [&](int KT, int BUF) {
#pragma unroll
        for (int c = 0; c < 4; ++c) {
            gll16(asrc[c] + KT * 64, &As[BUF][(t + 512 * c) * 8]);
            gll16(bsrc[c] + (size_t)KT * 8192, &Bs[BUF][(t + 512 * c) * 8]);
        }
    };

    const int lane = t & 63, wid = t >> 6;
    const int wm = wid >> 2, wn = wid & 3;  // rows wm*128, cols wn*64
    const int m16 = lane & 15, g = lane >> 4;
    int offA[8], offB[4];
#pragma unroll
    for (int i = 0; i < 8; ++i)
        offA[i] = IDX64(wm * 128 + i * 16 + m16, g);
#pragma unroll
    for (int j = 0; j < 4; ++j) {
        const int col = wn * 64 + j * 16 + m16;
        offB[j] = ((col >> 7) * 8192) + IDX64(col & 127, g);
    }

    const f32x4 zf = {0.f, 0.f, 0.f, 0.f};
    f32x4 acc[8][4];
#pragma unroll
    for (int i = 0; i < 8; ++i)
#pragma unroll
        for (int j = 0; j < 4; ++j) acc[i][j] = zf;

    stage(0, 0);
    stage(1, 1);

    for (int kt = 0; kt < 16; ++kt) {
        if (kt < 15) { asm volatile("s_waitcnt vmcnt(8)" ::: "memory"); }
        else         { asm volatile("s_waitcnt vmcnt(0)" ::: "memory"); }
        __builtin_amdgcn_s_barrier();
        const int cur = kt & 1;
        __builtin_amdgcn_s_setprio(1);
#pragma unroll
        for (int ks = 0; ks < 2; ++ks) {
            const int x = ks * 32;
            short8 af[8], bf[4];
#pragma unroll
            for (int i = 0; i < 8; ++i) af[i] = *(const short8*)&As[cur][offA[i] ^ x];
#pragma unroll
            for (int j = 0; j < 4; ++j) bf[j] = *(const short8*)&Bs[cur][offB[j] ^ x];
#pragma unroll
            for (int i = 0; i < 8; ++i)
#pragma unroll
                for (int j = 0; j < 4; ++j)
                    acc[i][j] = __builtin_amdgcn_mfma_f32_16x16x32_bf16(af[i], bf[j], acc[i][j], 0, 0, 0);
        }
        __builtin_amdgcn_s_setprio(0);
        if (kt < 14) {
            __builtin_amdgcn_s_barrier();
            asm volatile("" ::: "memory");
            stage(kt + 2, cur);
        }
    }

#pragma unroll
    for (int i = 0; i < 8; ++i) {
#pragma unroll
        for (int r = 0; r < 4; ++r) {
            const int grow = row0 + wm * 128 + i * 16 + g * 4 + r;
            if constexpr (MODE == 0) {
#pragma unroll
                for (int j = 0; j < 4; ++j) {
                    const int gcol = nbx * 256 + wn * 64 + j * 16 + m16;
                    out[(size_t)grow * D_MODEL + gcol] = acc[i][j][r] + B2[gcol];
                }
            } else {
                const bool valid = (grow - rstart) < rcount;
                if (!valid) continue;
                const int tok = rowid[grow];
                const float wt = rowwt[grow];
                const int sk = rowslot[grow];
                ushort* yr = Yb + (((size_t)sk * T_TOK + tok) << 10);
#pragma unroll
                for (int j = 0; j < 4; ++j) {
                    const int gcol = nbx * 256 + wn * 64 + j * 16 + m16;
                    yr[gcol] = f2bf(wt * (acc[i][j][r] + B2[gcol]));
                }
            }
        }
    }
}

// ---------------- out[tok] += Y[0][tok] + Y[1][tok] (dense, coalesced) -----
__global__ __launch_bounds__(256)
void k_combine(float* __restrict__ out, const ushort* __restrict__ Yb)
{
    const int row = blockIdx.x;            // 0..8191
    const int c = threadIdx.x * 4;
    float4 o = *(const float4*)(out + (size_t)row * 1024 + c);
    ushort4 y0 = *(const ushort4*)(Yb + (size_t)row * 1024 + c);
    ushort4 y1 = *(const ushort4*)(Yb + ((size_t)(T_TOK + row)) * 1024 + c);
    o.x += bf2f(y0.x) + bf2f(y1.x);
    o.y += bf2f(y0.y) + bf2f(y1.y);
    o.z += bf2f(y0.z) + bf2f(y1.z);
    o.w += bf2f(y0.w) + bf2f(y1.w);
    *(float4*)(out + (size_t)row * 1024 + c) = o;
}

// ---------------- launcher ----------------
// ws map (bytes) — unchanged (ws_size >= 86,507,520 proven):
//   [0,32)   cnt    [64,96) cnt2   [128,164) offs   [192,228) blk
//   [256,65792) topk_idx  [65792,131328) topk_w
//   [131328,200960) rowid [200960,270592) rowwt [270592,340224) rowslot
//   [524288, 36175872)  Hb  (ROWCAP*2048)
//   [36175872, 69730304) WA..WB (32 MB): w1t/w3t images; later Yb
//   [69730304, 86507520) WC (16 MB): Xbf until routed k_h done, then w2t
extern "C" void kernel_launch(void* const* d_in, const int* in_sizes, int n_in,
                              void* d_out, int out_size, void* d_ws, size_t ws_size,
                              hipStream_t stream)
{
    const float* x   = (const float*)d_in[0];
    const float* gw  = (const float*)d_in[1];
    const float* w1  = (const float*)d_in[2];
    const float* b1  = (const float*)d_in[3];
    const float* w2  = (const float*)d_in[4];
    const float* b2  = (const float*)d_in[5];
    const float* w3  = (const float*)d_in[6];
    const float* b3  = (const float*)d_in[7];
    const float* sw1 = (const float*)d_in[8];
    const float* sb1 = (const float*)d_in[9];
    const float* sw2 = (const float*)d_in[10];
    const float* sb2 = (const float*)d_in[11];
    const float* sw3 = (const float*)d_in[12];
    const float* sb3 = (const float*)d_in[13];
    float* out = (float*)d_out;

    char* ws = (char*)d_ws;
    int*   cnt      = (int*)(ws);
    int*   cnt2     = (int*)(ws + 64);
    int*   offs     = (int*)(ws + 128);
    int*   blk      = (int*)(ws + 192);
    int*   topk_idx = (int*)(ws + 256);
    float* topk_w   = (float*)(ws + 256 + 65536);
    int*   rowid    = (int*)(ws + 256 + 131072);
    float* rowwt    = (float*)(ws + 256 + 131072 + ROWCAP * 4);
    int*   rowslot  = (int*)(ws + 256 + 131072 + ROWCAP * 8);
    ushort* Hb = (ushort*)(ws + 524288);
    ushort* WA = (ushort*)(ws + 524288 + (size_t)ROWCAP * 2048); // 36,175,872
    ushort* WB = WA + (8u << 20);                                // +16 MB
    ushort* WC = WB + (8u << 20);                                // +16 MB

    ushort* sw1t = WB;
    ushort* sw3t = WB + (1 << 20);
    ushort* sw2t = WA;
    ushort* w1t  = WA;
    ushort* w3t  = WB;
    ushort* w2t  = WC;   // after Xbf dead
    ushort* Xbf  = WC;   // alive until routed k_h done
    ushort* Yb   = WA;   // 32 MB spanning WA+WB; w1t/w3t dead by routed k_out

    hipMemsetAsync(ws, 0, 256, stream);

    k_gate<<<256, 256, 0, stream>>>(x, gw, topk_idx, topk_w, cnt);
    k_prefix<<<1, 64, 0, stream>>>(cnt, offs, blk);
    k_scatter<<<32, 256, 0, stream>>>(topk_idx, topk_w, offs, cnt2, rowid, rowwt, rowslot);
    k_xbf<<<4096, 256, 0, stream>>>(x, Xbf);

    // shared expert
    k_tw<<<dim3(128, 2), 256, 0, stream>>>(sw1, sw1t, sw3, sw3t, 1);
    k_h<false><<<dim3(8, 32), 512, 0, stream>>>(Xbf, sw1t, sb1, sw3t, sb3, Hb,
                                                nullptr, nullptr, nullptr, nullptr);
    k_tw<<<dim3(128, 1), 256, 0, stream>>>(sw2, sw2t, sw2, sw2t, 1);
    k_out<0><<<dim3(4, 32), 512, 0, stream>>>(Hb, sw2t, sb2, out,
                                              nullptr, nullptr, nullptr, nullptr,
                                              nullptr, nullptr, nullptr);

    // routed experts
    k_tw<<<dim3(128, 16), 256, 0, stream>>>(w1, w1t, w3, w3t, 8);  // overwrites sw2t (dead)
    k_h<true><<<dim3(8, 72), 512, 0, stream>>>(Xbf, w1t, b1, w3t, b3, Hb,
                                               rowid, offs, blk, cnt);
    k_tw<<<dim3(128, 8), 256, 0, stream>>>(w2, w2t, w2, w2t, 8);   // overwrites Xbf (dead)
    k_out<2><<<dim3(4, 72), 512, 0, stream>>>(Hb, w2t, b2, out,
                                              rowid, offs, blk, cnt,
                                              rowwt, rowslot, Yb);
    k_combine<<<T_TOK, 256, 0, stream>>>(out, Yb);
}

// Round 6
// 426.549 us; speedup vs baseline: 1.2640x; 1.2180x over previous
//
#include <hip/hip_runtime.h>
#include <hip/hip_bf16.h>
#include <math.h>

#define D_MODEL 1024
#define INTER   1024
#define NEXP    8
#define T_TOK   8192
#define ROWCAP  17408   // 2*T + 8*127 padded up to 128

typedef short  short8 __attribute__((ext_vector_type(8)));
typedef float  f32x4  __attribute__((ext_vector_type(4)));

__device__ __forceinline__ ushort f2bf(float f) {
    uint u = __float_as_uint(f);
    u += 0x7fffu + ((u >> 16) & 1u);      // RNE (inputs finite)
    return (ushort)(u >> 16);
}
__device__ __forceinline__ float bf2f(ushort u) {
    return __uint_as_float((uint)u << 16);
}
__device__ __forceinline__ uint pk2(float lo, float hi) {
    return (uint)f2bf(lo) | ((uint)f2bf(hi) << 16);
}
__device__ __forceinline__ void gll16(const ushort* g, ushort* l) {
    __builtin_amdgcn_global_load_lds(
        (const __attribute__((address_space(1))) unsigned int*)(g),
        (__attribute__((address_space(3))) unsigned int*)(l), 16, 0, 0);
}

// tiled-swizzled LDS/weight image: 128 rows x 64 k bf16; row stride 64 ushort;
// logical 16B chunk c (0..7) of row r sits at image chunk c ^ (r & 7).
#define IDX64(r, c) ((r) * 64 + (((c) ^ ((r) & 7)) * 8))

// ---------------- gate: GW in regs, 8 tokens/wave; also emits bf16 X image --
__global__ __launch_bounds__(256)
void k_gate(const float* __restrict__ X, const float* __restrict__ GW,
            int* __restrict__ topk_idx, float* __restrict__ topk_w,
            int* __restrict__ cnt, ushort* __restrict__ Xb)
{
    __shared__ int lcnt[NEXP];
    const int t = threadIdx.x;
    if (t < NEXP) lcnt[t] = 0;
    const int lane = t & 63, wv = t >> 6;
    float4 gwr[NEXP][4];
#pragma unroll
    for (int e = 0; e < NEXP; ++e)
#pragma unroll
        for (int i = 0; i < 4; ++i)
            gwr[e][i] = *(const float4*)(GW + e * 1024 + i * 256 + lane * 4);
    __syncthreads();
    const int tok0 = blockIdx.x * 32 + wv * 8;
    const bool b0 = lane & 1, b1 = lane & 2, b2 = lane & 4;
    for (int tt = 0; tt < 8; ++tt) {
        const int tok = tok0 + tt;
        const float* xr = X + (size_t)tok * 1024;
        float4 xv[4];
#pragma unroll
        for (int i = 0; i < 4; ++i) xv[i] = *(const float4*)(xr + i * 256 + lane * 4);
        // fused fp32->bf16 X image write (replaces k_xbf; X already in regs)
#pragma unroll
        for (int i = 0; i < 4; ++i) {
            uint2 o = { pk2(xv[i].x, xv[i].y), pk2(xv[i].z, xv[i].w) };
            *(uint2*)(Xb + (size_t)tok * 1024 + i * 256 + lane * 4) = o;
        }
        float p[NEXP];
#pragma unroll
        for (int e = 0; e < NEXP; ++e) {
            float s = 0.f;
#pragma unroll
            for (int i = 0; i < 4; ++i)
                s += xv[i].x * gwr[e][i].x + xv[i].y * gwr[e][i].y
                   + xv[i].z * gwr[e][i].z + xv[i].w * gwr[e][i].w;
            p[e] = s;
        }
        float q[4];
#pragma unroll
        for (int j = 0; j < 4; ++j) {
            float send = b0 ? p[j] : p[j + 4];
            float recv = __shfl_xor(send, 1, 64);
            q[j] = (b0 ? p[j + 4] : p[j]) + recv;
        }
        float u2[2];
#pragma unroll
        for (int j = 0; j < 2; ++j) {
            float send = b1 ? q[j] : q[j + 2];
            float recv = __shfl_xor(send, 2, 64);
            u2[j] = (b1 ? q[j + 2] : q[j]) + recv;
        }
        float send = b2 ? u2[0] : u2[1];
        float r = (b2 ? u2[1] : u2[0]) + __shfl_xor(send, 4, 64);
        r += __shfl_xor(r, 8, 64);
        r += __shfl_xor(r, 16, 64);
        r += __shfl_xor(r, 32, 64);
        float sc[NEXP];
#pragma unroll
        for (int e = 0; e < NEXP; ++e)
            sc[e] = __shfl(r, ((e & 1) << 2) | (e & 2) | ((e >> 2) & 1), 64);
        float m = sc[0];
#pragma unroll
        for (int e = 1; e < NEXP; ++e) m = fmaxf(m, sc[e]);
        float ssum = 0.f;
#pragma unroll
        for (int e = 0; e < NEXP; ++e) { sc[e] = __expf(sc[e] - m); ssum += sc[e]; }
        float inv = 1.f / ssum;
#pragma unroll
        for (int e = 0; e < NEXP; ++e) sc[e] *= inv;
        int i0 = 0; float v0 = sc[0];
#pragma unroll
        for (int e = 1; e < NEXP; ++e) if (sc[e] > v0) { v0 = sc[e]; i0 = e; }
        int i1 = -1; float v1 = -1e30f;
#pragma unroll
        for (int e = 0; e < NEXP; ++e) if (e != i0 && sc[e] > v1) { v1 = sc[e]; i1 = e; }
        if (lane == 0) {
            topk_idx[2 * tok]     = i0;
            topk_idx[2 * tok + 1] = i1;
            topk_w[2 * tok]       = v0;
            topk_w[2 * tok + 1]   = v1;
            atomicAdd(&lcnt[i0], 1);
            atomicAdd(&lcnt[i1], 1);
        }
    }
    __syncthreads();
    if (t < NEXP) atomicAdd(&cnt[t], lcnt[t]);
}

__global__ void k_prefix(const int* __restrict__ cnt, int* __restrict__ offs)
{
    if (threadIdx.x == 0 && blockIdx.x == 0) {
        int tot = 0;
        for (int e = 0; e < NEXP; ++e) {
            offs[e] = tot;
            tot += ((cnt[e] + 127) / 128) * 128;
        }
        offs[NEXP] = tot;
    }
}

// scatter with block-aggregated atomics; also records which top-k slot (0/1)
__global__ void k_scatter(const int* __restrict__ topk_idx, const float* __restrict__ topk_w,
                          const int* __restrict__ offs, int* __restrict__ cnt2,
                          int* __restrict__ rowid, float* __restrict__ rowwt,
                          int* __restrict__ rowslot)
{
    __shared__ int loc[NEXP];
    __shared__ int base[NEXP];
    const int t = threadIdx.x;
    if (t < NEXP) loc[t] = 0;
    __syncthreads();
    const int tok = blockIdx.x * 256 + t;
    const int e0 = topk_idx[2 * tok], e1 = topk_idx[2 * tok + 1];
    const int s0 = atomicAdd(&loc[e0], 1);
    const int s1 = atomicAdd(&loc[e1], 1);
    __syncthreads();
    if (t < NEXP) base[t] = atomicAdd(&cnt2[t], loc[t]);
    __syncthreads();
    int p0 = offs[e0] + base[e0] + s0;
    rowid[p0] = tok; rowwt[p0] = topk_w[2 * tok]; rowslot[p0] = 0;
    int p1 = offs[e1] + base[e1] + s1;
    rowid[p1] = tok; rowwt[p1] = topk_w[2 * tok + 1]; rowslot[p1] = 1;
}

// ------- transpose fp32 [K][N] -> tiled swizzled bf16 (128n x 64k tiles) ----
// Up to 3 source groups: y < nA -> A[m], else y-nA < nB -> B[m], else C[m].
__global__ __launch_bounds__(256)
void k_tw(const float* __restrict__ srcA, ushort* __restrict__ dstA, int nA,
          const float* __restrict__ srcB, ushort* __restrict__ dstB, int nB,
          const float* __restrict__ srcC, ushort* __restrict__ dstC)
{
    __shared__ float tl[64][132];
    int m = blockIdx.y;
    const float* src; ushort* dst;
    if (m < nA)           { src = srcA + ((size_t)m << 20); dst = dstA + ((size_t)m << 20); }
    else if ((m -= nA) < nB) { src = srcB + ((size_t)m << 20); dst = dstB + ((size_t)m << 20); }
    else { m -= nB;       src = srcC + ((size_t)m << 20); dst = dstC + ((size_t)m << 20); }
    const int tile = blockIdx.x;            // nb*16 + kt
    const int nb = tile >> 4, kt = tile & 15;
    const int t = threadIdx.x;
    const int c4 = (t & 31) * 4, kr = t >> 5;
#pragma unroll
    for (int i = 0; i < 8; ++i) {
        const int kl = kr + 8 * i;
        float4 v = *(const float4*)(src + (size_t)(kt * 64 + kl) * 1024 + nb * 128 + c4);
        tl[kl][c4 + 0] = v.x; tl[kl][c4 + 1] = v.y;
        tl[kl][c4 + 2] = v.z; tl[kl][c4 + 3] = v.w;
    }
    __syncthreads();
    const int nl = t >> 1, h = t & 1;
    ushort* drow = dst + (size_t)tile * 8192 + nl * 64;
#pragma unroll
    for (int w = 0; w < 4; ++w) {
        const int cimg = h * 4 + w;
        const int cl = cimg ^ (nl & 7);
        float f[8];
#pragma unroll
        for (int j = 0; j < 8; ++j) f[j] = tl[cl * 8 + j][nl];
        uint4 o = { pk2(f[0], f[1]), pk2(f[2], f[3]), pk2(f[4], f[5]), pk2(f[6], f[7]) };
        *(uint4*)(drow + cimg * 8) = o;
    }
}

// ---------------- H = silu(X@W1+b1) * (X@W3+b3), BK=64, gll16 staging ------
// Round-2 proven structure (128x128 tile, 2 barriers/K-step, ~3 blocks/CU,
// implicit inter-block overlap) + T1 XCD-aware block swizzle.
template <bool ROUTED>
__global__ __launch_bounds__(256, 2)
void k_h(const ushort* __restrict__ Xb,
         const ushort* __restrict__ W1t, const float* __restrict__ B1,
         const ushort* __restrict__ W3t, const float* __restrict__ B3,
         ushort* __restrict__ Hb,
         const int* __restrict__ rowid, const int* __restrict__ offs,
         const int* __restrict__ cnt)
{
    __shared__ __align__(16) ushort As [128 * 64];
    __shared__ __align__(16) ushort B1s[128 * 64];
    __shared__ __align__(16) ushort B3s[128 * 64];
    __shared__ int ridc[128];

    // T1: bijective XCD swizzle (nwg = 8*gridDim.y, divisible by 8).
    // XCD c gets a contiguous band of row-blocks with all 8 col-blocks ->
    // A-panel L2-shared within the XCD.
    const int bid = blockIdx.y * 8 + blockIdx.x;
    const int swz = (bid & 7) * gridDim.y + (bid >> 3);
    const int nbx  = swz & 7;               // 0..7: 128-col block
    const int nb   = nbx * 128;
    const int row0 = (swz >> 3) * 128;

    int rstart = 0, rcount = T_TOK;
    const ushort* w1 = W1t; const ushort* w3 = W3t;
    if constexpr (ROUTED) {
        const int total = offs[NEXP];
        if (row0 >= total) return;
        int e = 0;
        while (offs[e + 1] <= row0) ++e;
        rstart = offs[e]; rcount = cnt[e];
        w1 += (size_t)e << 20; B1 += e * INTER;
        w3 += (size_t)e << 20; B3 += e * INTER;
    }
    const int t = threadIdx.x;
    const ushort* g1 = w1 + (size_t)(nbx * 16) * 8192 + t * 8;
    const ushort* g3 = w3 + (size_t)(nbx * 16) * 8192 + t * 8;

    // ---- A staging: per-lane inverse-swizzled global src, linear LDS dest --
    if constexpr (ROUTED) {
        if (t < 128) {
            const int rr = row0 + t;
            ridc[t] = ((rr - rstart) < rcount) ? rowid[rr] : 0;
        }
        __syncthreads();
    }
    const int sub = t >> 3, ci = t & 7;       // 8 threads cover one 128B row
    const ushort* asrc[4];
#pragma unroll
    for (int c = 0; c < 4; ++c) {
        const int r = c * 32 + sub;
        const int tok = ROUTED ? ridc[r] : (row0 + r);
        asrc[c] = Xb + (size_t)tok * 1024 + (size_t)((ci ^ (sub & 7)) * 8);
    }

    // fragment offsets
    const int lane = t & 63, wid = t >> 6;
    const int wm = wid & 1, wn = wid >> 1;
    const int m16 = lane & 15, g = lane >> 4;
    int offA[2][4], offB[2][4];
#pragma unroll
    for (int ks = 0; ks < 2; ++ks)
#pragma unroll
        for (int i = 0; i < 4; ++i) {
            offA[ks][i] = IDX64(wm * 64 + i * 16 + m16, ks * 4 + g);
            offB[ks][i] = IDX64(wn * 64 + i * 16 + m16, ks * 4 + g);
        }

    const f32x4 zf = {0.f, 0.f, 0.f, 0.f};
    f32x4 acc1[4][4], acc3[4][4];
#pragma unroll
    for (int i = 0; i < 4; ++i)
#pragma unroll
        for (int j = 0; j < 4; ++j) { acc1[i][j] = zf; acc3[i][j] = zf; }

    for (int kt = 0; kt < 16; ++kt) {
        __syncthreads();   // previous MFMA done reading LDS
#pragma unroll
        for (int c = 0; c < 4; ++c)
            gll16(asrc[c] + kt * 64, &As[c * 2048 + t * 8]);
#pragma unroll
        for (int c = 0; c < 4; ++c) {
            gll16(g1 + kt * 8192 + c * 2048, &B1s[c * 2048 + t * 8]);
            gll16(g3 + kt * 8192 + c * 2048, &B3s[c * 2048 + t * 8]);
        }
        __syncthreads();   // drains vmcnt (gll)
#pragma unroll
        for (int ks = 0; ks < 2; ++ks) {
            short8 af[4], b1f[4], b3f[4];
#pragma unroll
            for (int i = 0; i < 4; ++i) {
                af[i]  = *(const short8*)&As [offA[ks][i]];
                b1f[i] = *(const short8*)&B1s[offB[ks][i]];
                b3f[i] = *(const short8*)&B3s[offB[ks][i]];
            }
#pragma unroll
            for (int i = 0; i < 4; ++i)
#pragma unroll
                for (int j = 0; j < 4; ++j) {
                    acc1[i][j] = __builtin_amdgcn_mfma_f32_16x16x32_bf16(af[i], b1f[j], acc1[i][j], 0, 0, 0);
                    acc3[i][j] = __builtin_amdgcn_mfma_f32_16x16x32_bf16(af[i], b3f[j], acc3[i][j], 0, 0, 0);
                }
        }
    }

#pragma unroll
    for (int j = 0; j < 4; ++j) {
        const int gcol = nb + wn * 64 + j * 16 + m16;
        const float bb1 = B1[gcol];
        const float bb3 = B3[gcol];
#pragma unroll
        for (int i = 0; i < 4; ++i) {
            const int growb = row0 + wm * 64 + i * 16 + g * 4;
#pragma unroll
            for (int r = 0; r < 4; ++r) {
                float x1 = acc1[i][j][r] + bb1;
                float x3 = acc3[i][j][r] + bb3;
                float h = x1 / (1.f + __expf(-x1)) * x3;
                Hb[(size_t)(growb + r) * INTER + gcol] = f2bf(h);
            }
        }
    }
}

// ---------------- out epilogue modes:
//   MODE 0: shared expert  -> plain store to out
//   MODE 2: routed, race-free weighted bf16 store into Y[slot][tok][col]
template <int MODE>
__global__ __launch_bounds__(256, 2)
void k_out(const ushort* __restrict__ Hin,
           const ushort* __restrict__ W2t, const float* __restrict__ B2,
           float* __restrict__ out,
           const int* __restrict__ rowid, const int* __restrict__ offs,
           const int* __restrict__ cnt, const float* __restrict__ rowwt,
           const int* __restrict__ rowslot, ushort* __restrict__ Yb)
{
    __shared__ __align__(16) ushort As[128 * 64];
    __shared__ __align__(16) ushort Bs[128 * 64];

    const int bid = blockIdx.y * 8 + blockIdx.x;
    const int swz = (bid & 7) * gridDim.y + (bid >> 3);
    const int nbx  = swz & 7;
    const int nb   = nbx * 128;
    const int row0 = (swz >> 3) * 128;

    int rstart = 0, rcount = T_TOK;
    const ushort* w2 = W2t;
    if constexpr (MODE != 0) {
        const int total = offs[NEXP];
        if (row0 >= total) return;
        int e = 0;
        while (offs[e + 1] <= row0) ++e;
        rstart = offs[e]; rcount = cnt[e];
        w2 += (size_t)e << 20; B2 += e * D_MODEL;
    }
    const int t = threadIdx.x;
    const ushort* g2 = w2 + (size_t)(nbx * 16) * 8192 + t * 8;

    // A staging: per-lane inverse-swizzled source, linear LDS dest
    const int sub = t >> 3, ci = t & 7;
    const ushort* asrc[4];
#pragma unroll
    for (int c = 0; c < 4; ++c) {
        const int r = c * 32 + sub;
        asrc[c] = Hin + (size_t)(row0 + r) * 1024 + (size_t)((ci ^ (sub & 7)) * 8);
    }

    const int lane = t & 63, wid = t >> 6;
    const int wm = wid & 1, wn = wid >> 1;
    const int m16 = lane & 15, g = lane >> 4;
    int offA[2][4], offB[2][4];
#pragma unroll
    for (int ks = 0; ks < 2; ++ks)
#pragma unroll
        for (int i = 0; i < 4; ++i) {
            offA[ks][i] = IDX64(wm * 64 + i * 16 + m16, ks * 4 + g);
            offB[ks][i] = IDX64(wn * 64 + i * 16 + m16, ks * 4 + g);
        }

    const f32x4 zf = {0.f, 0.f, 0.f, 0.f};
    f32x4 acc[4][4];
#pragma unroll
    for (int i = 0; i < 4; ++i)
#pragma unroll
        for (int j = 0; j < 4; ++j) acc[i][j] = zf;

    for (int kt = 0; kt < 16; ++kt) {
        __syncthreads();
#pragma unroll
        for (int c = 0; c < 4; ++c)
            gll16(asrc[c] + kt * 64, &As[c * 2048 + t * 8]);
#pragma unroll
        for (int c = 0; c < 4; ++c)
            gll16(g2 + kt * 8192 + c * 2048, &Bs[c * 2048 + t * 8]);
        __syncthreads();
#pragma unroll
        for (int ks = 0; ks < 2; ++ks) {
            short8 af[4], bf[4];
#pragma unroll
            for (int i = 0; i < 4; ++i) {
                af[i] = *(const short8*)&As[offA[ks][i]];
                bf[i] = *(const short8*)&Bs[offB[ks][i]];
            }
#pragma unroll
            for (int i = 0; i < 4; ++i)
#pragma unroll
                for (int j = 0; j < 4; ++j)
                    acc[i][j] = __builtin_amdgcn_mfma_f32_16x16x32_bf16(af[i], bf[j], acc[i][j], 0, 0, 0);
        }
    }

#pragma unroll
    for (int i = 0; i < 4; ++i) {
#pragma unroll
        for (int r = 0; r < 4; ++r) {
            const int grow = row0 + wm * 64 + i * 16 + g * 4 + r;
            if constexpr (MODE == 0) {
#pragma unroll
                for (int j = 0; j < 4; ++j) {
                    const int gcol = nb + wn * 64 + j * 16 + m16;
                    out[(size_t)grow * D_MODEL + gcol] = acc[i][j][r] + B2[gcol];
                }
            } else {
                const bool valid = (grow - rstart) < rcount;
                if (!valid) continue;
                const int tok = rowid[grow];
                const float wt = rowwt[grow];
                const int sk = rowslot[grow];
                ushort* yr = Yb + (((size_t)sk * T_TOK + tok) << 10);
#pragma unroll
                for (int j = 0; j < 4; ++j) {
                    const int gcol = nb + wn * 64 + j * 16 + m16;
                    yr[gcol] = f2bf(wt * (acc[i][j][r] + B2[gcol]));
                }
            }
        }
    }
}

// ---------------- out[tok] += Y[0][tok] + Y[1][tok] (dense, coalesced) -----
__global__ __launch_bounds__(256)
void k_combine(float* __restrict__ out, const ushort* __restrict__ Yb)
{
    const int row = blockIdx.x;            // 0..8191
    const int c = threadIdx.x * 4;
    float4 o = *(const float4*)(out + (size_t)row * 1024 + c);
    ushort4 y0 = *(const ushort4*)(Yb + (size_t)row * 1024 + c);
    ushort4 y1 = *(const ushort4*)(Yb + ((size_t)(T_TOK + row)) * 1024 + c);
    o.x += bf2f(y0.x) + bf2f(y1.x);
    o.y += bf2f(y0.y) + bf2f(y1.y);
    o.z += bf2f(y0.z) + bf2f(y1.z);
    o.w += bf2f(y0.w) + bf2f(y1.w);
    *(float4*)(out + (size_t)row * 1024 + c) = o;
}

// ---------------- launcher ----------------
// ws map (bytes), ws_size >= 86,507,520 proven across rounds 2-5:
//   [0,32)   cnt    [64,96) cnt2   [128,164) offs
//   [256,65792) topk_idx  [65792,131328) topk_w
//   [131328,200960) rowid [200960,270592) rowwt [270592,340224) rowslot
//   [524288, 36175872)  Hb  (ROWCAP*2048)
//   [36175872, 69730304) WA..WB (32 MB): w1t/w3t images; later Yb
//   [69730304, 86507520) WC (16 MB): Xbf until routed k_h done, then w2t
extern "C" void kernel_launch(void* const* d_in, const int* in_sizes, int n_in,
                              void* d_out, int out_size, void* d_ws, size_t ws_size,
                              hipStream_t stream)
{
    const float* x   = (const float*)d_in[0];
    const float* gw  = (const float*)d_in[1];
    const float* w1  = (const float*)d_in[2];
    const float* b1  = (const float*)d_in[3];
    const float* w2  = (const float*)d_in[4];
    const float* b2  = (const float*)d_in[5];
    const float* w3  = (const float*)d_in[6];
    const float* b3  = (const float*)d_in[7];
    const float* sw1 = (const float*)d_in[8];
    const float* sb1 = (const float*)d_in[9];
    const float* sw2 = (const float*)d_in[10];
    const float* sb2 = (const float*)d_in[11];
    const float* sw3 = (const float*)d_in[12];
    const float* sb3 = (const float*)d_in[13];
    float* out = (float*)d_out;

    char* ws = (char*)d_ws;
    int*   cnt      = (int*)(ws);
    int*   cnt2     = (int*)(ws + 64);
    int*   offs     = (int*)(ws + 128);
    int*   topk_idx = (int*)(ws + 256);
    float* topk_w   = (float*)(ws + 256 + 65536);
    int*   rowid    = (int*)(ws + 256 + 131072);
    float* rowwt    = (float*)(ws + 256 + 131072 + ROWCAP * 4);
    int*   rowslot  = (int*)(ws + 256 + 131072 + ROWCAP * 8);
    ushort* Hb = (ushort*)(ws + 524288);
    ushort* WA = (ushort*)(ws + 524288 + (size_t)ROWCAP * 2048); // 36,175,872
    ushort* WB = WA + (8u << 20);                                // +16 MB
    ushort* WC = WB + (8u << 20);                                // +16 MB

    ushort* sw1t = WB;
    ushort* sw3t = WB + (1 << 20);
    ushort* sw2t = WA;
    ushort* w1t  = WA;
    ushort* w3t  = WB;
    ushort* w2t  = WC;   // after Xbf dead
    ushort* Xbf  = WC;   // alive until routed k_h done
    ushort* Yb   = WA;   // 32 MB spanning WA+WB; w1t/w3t dead by routed k_out

    hipMemsetAsync(ws, 0, 256, stream);

    k_gate<<<256, 256, 0, stream>>>(x, gw, topk_idx, topk_w, cnt, Xbf);
    k_prefix<<<1, 64, 0, stream>>>(cnt, offs);
    k_scatter<<<32, 256, 0, stream>>>(topk_idx, topk_w, offs, cnt2, rowid, rowwt, rowslot);

    // shared expert (all three shared transposes in one launch)
    k_tw<<<dim3(128, 3), 256, 0, stream>>>(sw1, sw1t, 1, sw3, sw3t, 1, sw2, sw2t);
    k_h<false><<<dim3(8, 64), 256, 0, stream>>>(Xbf, sw1t, sb1, sw3t, sb3, Hb,
                                                nullptr, nullptr, nullptr);
    k_out<0><<<dim3(8, 64), 256, 0, stream>>>(Hb, sw2t, sb2, out,
                                              nullptr, nullptr, nullptr, nullptr,
                                              nullptr, nullptr);

    // routed experts
    k_tw<<<dim3(128, 16), 256, 0, stream>>>(w1, w1t, 8, w3, w3t, 8, nullptr, nullptr);
    k_h<true><<<dim3(8, ROWCAP / 128), 256, 0, stream>>>(Xbf, w1t, b1, w3t, b3, Hb,
                                                         rowid, offs, cnt);
    k_tw<<<dim3(128, 8), 256, 0, stream>>>(w2, w2t, 8, nullptr, nullptr, 0,
                                           nullptr, nullptr);   // overwrites Xbf (dead)
    k_out<2><<<dim3(8, ROWCAP / 128), 256, 0, stream>>>(Hb, w2t, b2, out,
                                                        rowid, offs, cnt, rowwt,
                                                        rowslot, Yb);
    k_combine<<<T_TOK, 256, 0, stream>>>(out, Yb);
}

// Round 7
// 414.925 us; speedup vs baseline: 1.2995x; 1.0280x over previous
//
#include <hip/hip_runtime.h>
#include <hip/hip_bf16.h>
#include <math.h>

#define D_MODEL 1024
#define INTER   1024
#define NEXP    8
#define T_TOK   8192
#define ROWCAP  17408   // 2*T + 8*127 padded up to 128

typedef short  short8 __attribute__((ext_vector_type(8)));
typedef float  f32x4  __attribute__((ext_vector_type(4)));

__device__ __forceinline__ ushort f2bf(float f) {
    uint u = __float_as_uint(f);
    u += 0x7fffu + ((u >> 16) & 1u);      // RNE (inputs finite)
    return (ushort)(u >> 16);
}
__device__ __forceinline__ float bf2f(ushort u) {
    return __uint_as_float((uint)u << 16);
}
__device__ __forceinline__ uint pk2(float lo, float hi) {
    return (uint)f2bf(lo) | ((uint)f2bf(hi) << 16);
}
__device__ __forceinline__ void gll16(const ushort* g, ushort* l) {
    __builtin_amdgcn_global_load_lds(
        (const __attribute__((address_space(1))) unsigned int*)(g),
        (__attribute__((address_space(3))) unsigned int*)(l), 16, 0, 0);
}

// tiled-swizzled LDS/weight image: rows x 64 k bf16; row stride 64 ushort;
// logical 16B chunk c (0..7) of row r sits at image chunk c ^ (r & 7).
#define IDX64(r, c) ((r) * 64 + (((c) ^ ((r) & 7)) * 8))

// ---------------- gate: GW in regs, 8 tokens/wave; also emits bf16 X image --
__global__ __launch_bounds__(256)
void k_gate(const float* __restrict__ X, const float* __restrict__ GW,
            int* __restrict__ topk_idx, float* __restrict__ topk_w,
            int* __restrict__ cnt, ushort* __restrict__ Xb)
{
    __shared__ int lcnt[NEXP];
    const int t = threadIdx.x;
    if (t < NEXP) lcnt[t] = 0;
    const int lane = t & 63, wv = t >> 6;
    float4 gwr[NEXP][4];
#pragma unroll
    for (int e = 0; e < NEXP; ++e)
#pragma unroll
        for (int i = 0; i < 4; ++i)
            gwr[e][i] = *(const float4*)(GW + e * 1024 + i * 256 + lane * 4);
    __syncthreads();
    const int tok0 = blockIdx.x * 32 + wv * 8;
    const bool b0 = lane & 1, b1 = lane & 2, b2 = lane & 4;
    for (int tt = 0; tt < 8; ++tt) {
        const int tok = tok0 + tt;
        const float* xr = X + (size_t)tok * 1024;
        float4 xv[4];
#pragma unroll
        for (int i = 0; i < 4; ++i) xv[i] = *(const float4*)(xr + i * 256 + lane * 4);
        // fused fp32->bf16 X image write (X already in regs)
#pragma unroll
        for (int i = 0; i < 4; ++i) {
            uint2 o = { pk2(xv[i].x, xv[i].y), pk2(xv[i].z, xv[i].w) };
            *(uint2*)(Xb + (size_t)tok * 1024 + i * 256 + lane * 4) = o;
        }
        float p[NEXP];
#pragma unroll
        for (int e = 0; e < NEXP; ++e) {
            float s = 0.f;
#pragma unroll
            for (int i = 0; i < 4; ++i)
                s += xv[i].x * gwr[e][i].x + xv[i].y * gwr[e][i].y
                   + xv[i].z * gwr[e][i].z + xv[i].w * gwr[e][i].w;
            p[e] = s;
        }
        float q[4];
#pragma unroll
        for (int j = 0; j < 4; ++j) {
            float send = b0 ? p[j] : p[j + 4];
            float recv = __shfl_xor(send, 1, 64);
            q[j] = (b0 ? p[j + 4] : p[j]) + recv;
        }
        float u2[2];
#pragma unroll
        for (int j = 0; j < 2; ++j) {
            float send = b1 ? q[j] : q[j + 2];
            float recv = __shfl_xor(send, 2, 64);
            u2[j] = (b1 ? q[j + 2] : q[j]) + recv;
        }
        float send = b2 ? u2[0] : u2[1];
        float r = (b2 ? u2[1] : u2[0]) + __shfl_xor(send, 4, 64);
        r += __shfl_xor(r, 8, 64);
        r += __shfl_xor(r, 16, 64);
        r += __shfl_xor(r, 32, 64);
        float sc[NEXP];
#pragma unroll
        for (int e = 0; e < NEXP; ++e)
            sc[e] = __shfl(r, ((e & 1) << 2) | (e & 2) | ((e >> 2) & 1), 64);
        float m = sc[0];
#pragma unroll
        for (int e = 1; e < NEXP; ++e) m = fmaxf(m, sc[e]);
        float ssum = 0.f;
#pragma unroll
        for (int e = 0; e < NEXP; ++e) { sc[e] = __expf(sc[e] - m); ssum += sc[e]; }
        float inv = 1.f / ssum;
#pragma unroll
        for (int e = 0; e < NEXP; ++e) sc[e] *= inv;
        int i0 = 0; float v0 = sc[0];
#pragma unroll
        for (int e = 1; e < NEXP; ++e) if (sc[e] > v0) { v0 = sc[e]; i0 = e; }
        int i1 = -1; float v1 = -1e30f;
#pragma unroll
        for (int e = 0; e < NEXP; ++e) if (e != i0 && sc[e] > v1) { v1 = sc[e]; i1 = e; }
        if (lane == 0) {
            topk_idx[2 * tok]     = i0;
            topk_idx[2 * tok + 1] = i1;
            topk_w[2 * tok]       = v0;
            topk_w[2 * tok + 1]   = v1;
            atomicAdd(&lcnt[i0], 1);
            atomicAdd(&lcnt[i1], 1);
        }
    }
    __syncthreads();
    if (t < NEXP) atomicAdd(&cnt[t], lcnt[t]);
}

__global__ void k_prefix(const int* __restrict__ cnt, int* __restrict__ offs)
{
    if (threadIdx.x == 0 && blockIdx.x == 0) {
        int tot = 0;
        for (int e = 0; e < NEXP; ++e) {
            offs[e] = tot;
            tot += ((cnt[e] + 127) / 128) * 128;
        }
        offs[NEXP] = tot;
    }
}

// scatter with block-aggregated atomics; also records which top-k slot (0/1)
__global__ void k_scatter(const int* __restrict__ topk_idx, const float* __restrict__ topk_w,
                          const int* __restrict__ offs, int* __restrict__ cnt2,
                          int* __restrict__ rowid, float* __restrict__ rowwt,
                          int* __restrict__ rowslot)
{
    __shared__ int loc[NEXP];
    __shared__ int base[NEXP];
    const int t = threadIdx.x;
    if (t < NEXP) loc[t] = 0;
    __syncthreads();
    const int tok = blockIdx.x * 256 + t;
    const int e0 = topk_idx[2 * tok], e1 = topk_idx[2 * tok + 1];
    const int s0 = atomicAdd(&loc[e0], 1);
    const int s1 = atomicAdd(&loc[e1], 1);
    __syncthreads();
    if (t < NEXP) base[t] = atomicAdd(&cnt2[t], loc[t]);
    __syncthreads();
    int p0 = offs[e0] + base[e0] + s0;
    rowid[p0] = tok; rowwt[p0] = topk_w[2 * tok]; rowslot[p0] = 0;
    int p1 = offs[e1] + base[e1] + s1;
    rowid[p1] = tok; rowwt[p1] = topk_w[2 * tok + 1]; rowslot[p1] = 1;
}

// ------- transpose fp32 [K][N] -> tiled swizzled bf16 (128n x 64k tiles) ----
// Up to 5 source groups so all weight transposes fit in one launch.
__global__ __launch_bounds__(256)
void k_tw(const float* __restrict__ s1, ushort* __restrict__ d1, int n1,
          const float* __restrict__ s2, ushort* __restrict__ d2, int n2,
          const float* __restrict__ s3, ushort* __restrict__ d3, int n3,
          const float* __restrict__ s4, ushort* __restrict__ d4, int n4,
          const float* __restrict__ s5, ushort* __restrict__ d5)
{
    __shared__ float tl[64][132];
    int m = blockIdx.y;
    const float* src; ushort* dst;
    if (m < n1)              { src = s1 + ((size_t)m << 20); dst = d1 + ((size_t)m << 20); }
    else if ((m -= n1) < n2) { src = s2 + ((size_t)m << 20); dst = d2 + ((size_t)m << 20); }
    else if ((m -= n2) < n3) { src = s3 + ((size_t)m << 20); dst = d3 + ((size_t)m << 20); }
    else if ((m -= n3) < n4) { src = s4 + ((size_t)m << 20); dst = d4 + ((size_t)m << 20); }
    else { m -= n4;            src = s5 + ((size_t)m << 20); dst = d5 + ((size_t)m << 20); }
    const int tile = blockIdx.x;            // nb*16 + kt
    const int nb = tile >> 4, kt = tile & 15;
    const int t = threadIdx.x;
    const int c4 = (t & 31) * 4, kr = t >> 5;
#pragma unroll
    for (int i = 0; i < 8; ++i) {
        const int kl = kr + 8 * i;
        float4 v = *(const float4*)(src + (size_t)(kt * 64 + kl) * 1024 + nb * 128 + c4);
        tl[kl][c4 + 0] = v.x; tl[kl][c4 + 1] = v.y;
        tl[kl][c4 + 2] = v.z; tl[kl][c4 + 3] = v.w;
    }
    __syncthreads();
    const int nl = t >> 1, h = t & 1;
    ushort* drow = dst + (size_t)tile * 8192 + nl * 64;
#pragma unroll
    for (int w = 0; w < 4; ++w) {
        const int cimg = h * 4 + w;
        const int cl = cimg ^ (nl & 7);
        float f[8];
#pragma unroll
        for (int j = 0; j < 8; ++j) f[j] = tl[cl * 8 + j][nl];
        uint4 o = { pk2(f[0], f[1]), pk2(f[2], f[3]), pk2(f[4], f[5]), pk2(f[6], f[7]) };
        *(uint4*)(drow + cimg * 8) = o;
    }
}

// ---------------- H = silu(X@W1+b1) * (X@W3+b3), 128x64 tile, BK=64 --------
// Re-partitioned for occupancy: per-wave acc = 16 f32x4 (64 regs) -> ~4
// desynced blocks/CU (m114 inter-block overlap). 16 col-blocks; B-tile is a
// contiguous 64-col half of the 128-col weight-image tile (pointer math only).
template <bool ROUTED>
__global__ __launch_bounds__(256, 3)
void k_h(const ushort* __restrict__ Xb,
         const ushort* __restrict__ W1t, const float* __restrict__ B1,
         const ushort* __restrict__ W3t, const float* __restrict__ B3,
         ushort* __restrict__ Hb,
         const int* __restrict__ rowid, const int* __restrict__ offs,
         const int* __restrict__ cnt)
{
    __shared__ __align__(16) ushort As [128 * 64];   // 16 KB
    __shared__ __align__(16) ushort B1s[64 * 64];    // 8 KB
    __shared__ __align__(16) ushort B3s[64 * 64];    // 8 KB
    __shared__ int ridc[128];

    // T1 bijective XCD swizzle: all 16 col-blocks of a row-block land on one
    // XCD band (A-panel L2-shared). nwg = 16*gridDim.y, divisible by 8.
    const int bid = blockIdx.y * 16 + blockIdx.x;
    const int swz = (bid & 7) * (gridDim.y * 2) + (bid >> 3);
    const int nbx  = swz & 15;              // 0..15: 64-col block
    const int row0 = (swz >> 4) * 128;

    int rstart = 0, rcount = T_TOK;
    const ushort* w1 = W1t; const ushort* w3 = W3t;
    if constexpr (ROUTED) {
        const int total = offs[NEXP];
        if (row0 >= total) return;
        int e = 0;
        while (offs[e + 1] <= row0) ++e;
        rstart = offs[e]; rcount = cnt[e];
        w1 += (size_t)e << 20; B1 += e * INTER;
        w3 += (size_t)e << 20; B3 += e * INTER;
    }
    const int t = threadIdx.x;
    // 64-col half of image tile nbx>>1: rows (nbx&1)*64.. = +4096 ushorts
    const ushort* g1 = w1 + (size_t)(nbx >> 1) * 131072 + (nbx & 1) * 4096 + t * 8;
    const ushort* g3 = w3 + (size_t)(nbx >> 1) * 131072 + (nbx & 1) * 4096 + t * 8;

    // A staging: per-lane inverse-swizzled global src, linear LDS dest
    if constexpr (ROUTED) {
        if (t < 128) {
            const int rr = row0 + t;
            ridc[t] = ((rr - rstart) < rcount) ? rowid[rr] : 0;
        }
        __syncthreads();
    }
    const int sub = t >> 3, ci = t & 7;       // 8 threads cover one 128B row
    const ushort* asrc[4];
#pragma unroll
    for (int c = 0; c < 4; ++c) {
        const int r = c * 32 + sub;
        const int tok = ROUTED ? ridc[r] : (row0 + r);
        asrc[c] = Xb + (size_t)tok * 1024 + (size_t)((ci ^ (sub & 7)) * 8);
    }

    // fragment offsets; waves 2x2: rows wm*64, cols wn*32
    const int lane = t & 63, wid = t >> 6;
    const int wm = wid & 1, wn = wid >> 1;
    const int m16 = lane & 15, g = lane >> 4;
    int offA[2][4], offB[2][2];
#pragma unroll
    for (int ks = 0; ks < 2; ++ks) {
#pragma unroll
        for (int i = 0; i < 4; ++i)
            offA[ks][i] = IDX64(wm * 64 + i * 16 + m16, ks * 4 + g);
#pragma unroll
        for (int j = 0; j < 2; ++j)
            offB[ks][j] = IDX64(wn * 32 + j * 16 + m16, ks * 4 + g);
    }

    const f32x4 zf = {0.f, 0.f, 0.f, 0.f};
    f32x4 acc1[4][2], acc3[4][2];
#pragma unroll
    for (int i = 0; i < 4; ++i)
#pragma unroll
        for (int j = 0; j < 2; ++j) { acc1[i][j] = zf; acc3[i][j] = zf; }

    for (int kt = 0; kt < 16; ++kt) {
        __syncthreads();   // previous MFMA done reading LDS
#pragma unroll
        for (int c = 0; c < 4; ++c)
            gll16(asrc[c] + kt * 64, &As[c * 2048 + t * 8]);
#pragma unroll
        for (int c = 0; c < 2; ++c) {
            gll16(g1 + (size_t)kt * 8192 + c * 2048, &B1s[c * 2048 + t * 8]);
            gll16(g3 + (size_t)kt * 8192 + c * 2048, &B3s[c * 2048 + t * 8]);
        }
        __syncthreads();   // drains vmcnt (gll)
#pragma unroll
        for (int ks = 0; ks < 2; ++ks) {
            short8 af[4], b1f[2], b3f[2];
#pragma unroll
            for (int i = 0; i < 4; ++i) af[i] = *(const short8*)&As[offA[ks][i]];
#pragma unroll
            for (int j = 0; j < 2; ++j) {
                b1f[j] = *(const short8*)&B1s[offB[ks][j]];
                b3f[j] = *(const short8*)&B3s[offB[ks][j]];
            }
#pragma unroll
            for (int i = 0; i < 4; ++i)
#pragma unroll
                for (int j = 0; j < 2; ++j) {
                    acc1[i][j] = __builtin_amdgcn_mfma_f32_16x16x32_bf16(af[i], b1f[j], acc1[i][j], 0, 0, 0);
                    acc3[i][j] = __builtin_amdgcn_mfma_f32_16x16x32_bf16(af[i], b3f[j], acc3[i][j], 0, 0, 0);
                }
        }
    }

#pragma unroll
    for (int j = 0; j < 2; ++j) {
        const int gcol = nbx * 64 + wn * 32 + j * 16 + m16;
        const float bb1 = B1[gcol];
        const float bb3 = B3[gcol];
#pragma unroll
        for (int i = 0; i < 4; ++i) {
            const int growb = row0 + wm * 64 + i * 16 + g * 4;
#pragma unroll
            for (int r = 0; r < 4; ++r) {
                float x1 = acc1[i][j][r] + bb1;
                float x3 = acc3[i][j][r] + bb3;
                float h = x1 / (1.f + __expf(-x1)) * x3;
                Hb[(size_t)(growb + r) * INTER + gcol] = f2bf(h);
            }
        }
    }
}

// ---------------- out = H@W2 + b2, 128x64 tile ------------------------------
//   MODE 0: shared expert  -> plain store to out
//   MODE 2: routed, race-free weighted bf16 store into Y[slot][tok][col]
template <int MODE>
__global__ __launch_bounds__(256, 3)
void k_out(const ushort* __restrict__ Hin,
           const ushort* __restrict__ W2t, const float* __restrict__ B2,
           float* __restrict__ out,
           const int* __restrict__ rowid, const int* __restrict__ offs,
           const int* __restrict__ cnt, const float* __restrict__ rowwt,
           const int* __restrict__ rowslot, ushort* __restrict__ Yb)
{
    __shared__ __align__(16) ushort As[128 * 64];
    __shared__ __align__(16) ushort Bs[64 * 64];

    const int bid = blockIdx.y * 16 + blockIdx.x;
    const int swz = (bid & 7) * (gridDim.y * 2) + (bid >> 3);
    const int nbx  = swz & 15;
    const int row0 = (swz >> 4) * 128;

    int rstart = 0, rcount = T_TOK;
    const ushort* w2 = W2t;
    if constexpr (MODE != 0) {
        const int total = offs[NEXP];
        if (row0 >= total) return;
        int e = 0;
        while (offs[e + 1] <= row0) ++e;
        rstart = offs[e]; rcount = cnt[e];
        w2 += (size_t)e << 20; B2 += e * D_MODEL;
    }
    const int t = threadIdx.x;
    const ushort* g2 = w2 + (size_t)(nbx >> 1) * 131072 + (nbx & 1) * 4096 + t * 8;

    // A staging: per-lane inverse-swizzled source, linear LDS dest
    const int sub = t >> 3, ci = t & 7;
    const ushort* asrc[4];
#pragma unroll
    for (int c = 0; c < 4; ++c) {
        const int r = c * 32 + sub;
        asrc[c] = Hin + (size_t)(row0 + r) * 1024 + (size_t)((ci ^ (sub & 7)) * 8);
    }

    const int lane = t & 63, wid = t >> 6;
    const int wm = wid & 1, wn = wid >> 1;
    const int m16 = lane & 15, g = lane >> 4;
    int offA[2][4], offB[2][2];
#pragma unroll
    for (int ks = 0; ks < 2; ++ks) {
#pragma unroll
        for (int i = 0; i < 4; ++i)
            offA[ks][i] = IDX64(wm * 64 + i * 16 + m16, ks * 4 + g);
#pragma unroll
        for (int j = 0; j < 2; ++j)
            offB[ks][j] = IDX64(wn * 32 + j * 16 + m16, ks * 4 + g);
    }

    const f32x4 zf = {0.f, 0.f, 0.f, 0.f};
    f32x4 acc[4][2];
#pragma unroll
    for (int i = 0; i < 4; ++i)
#pragma unroll
        for (int j = 0; j < 2; ++j) acc[i][j] = zf;

    for (int kt = 0; kt < 16; ++kt) {
        __syncthreads();
#pragma unroll
        for (int c = 0; c < 4; ++c)
            gll16(asrc[c] + kt * 64, &As[c * 2048 + t * 8]);
#pragma unroll
        for (int c = 0; c < 2; ++c)
            gll16(g2 + (size_t)kt * 8192 + c * 2048, &Bs[c * 2048 + t * 8]);
        __syncthreads();
#pragma unroll
        for (int ks = 0; ks < 2; ++ks) {
            short8 af[4], bf[2];
#pragma unroll
            for (int i = 0; i < 4; ++i) af[i] = *(const short8*)&As[offA[ks][i]];
#pragma unroll
            for (int j = 0; j < 2; ++j) bf[j] = *(const short8*)&Bs[offB[ks][j]];
#pragma unroll
            for (int i = 0; i < 4; ++i)
#pragma unroll
                for (int j = 0; j < 2; ++j)
                    acc[i][j] = __builtin_amdgcn_mfma_f32_16x16x32_bf16(af[i], bf[j], acc[i][j], 0, 0, 0);
        }
    }

#pragma unroll
    for (int i = 0; i < 4; ++i) {
#pragma unroll
        for (int r = 0; r < 4; ++r) {
            const int grow = row0 + wm * 64 + i * 16 + g * 4 + r;
            if constexpr (MODE == 0) {
#pragma unroll
                for (int j = 0; j < 2; ++j) {
                    const int gcol = nbx * 64 + wn * 32 + j * 16 + m16;
                    out[(size_t)grow * D_MODEL + gcol] = acc[i][j][r] + B2[gcol];
                }
            } else {
                const bool valid = (grow - rstart) < rcount;
                if (!valid) continue;
                const int tok = rowid[grow];
                const float wt = rowwt[grow];
                const int sk = rowslot[grow];
                ushort* yr = Yb + (((size_t)sk * T_TOK + tok) << 10);
#pragma unroll
                for (int j = 0; j < 2; ++j) {
                    const int gcol = nbx * 64 + wn * 32 + j * 16 + m16;
                    yr[gcol] = f2bf(wt * (acc[i][j][r] + B2[gcol]));
                }
            }
        }
    }
}

// ---------------- out[tok] += Y[0][tok] + Y[1][tok] (dense, coalesced) -----
__global__ __launch_bounds__(256)
void k_combine(float* __restrict__ out, const ushort* __restrict__ Yb)
{
    const int row = blockIdx.x;            // 0..8191
    const int c = threadIdx.x * 4;
    float4 o = *(const float4*)(out + (size_t)row * 1024 + c);
    ushort4 y0 = *(const ushort4*)(Yb + (size_t)row * 1024 + c);
    ushort4 y1 = *(const ushort4*)(Yb + ((size_t)(T_TOK + row)) * 1024 + c);
    o.x += bf2f(y0.x) + bf2f(y1.x);
    o.y += bf2f(y0.y) + bf2f(y1.y);
    o.z += bf2f(y0.z) + bf2f(y1.z);
    o.w += bf2f(y0.w) + bf2f(y1.w);
    *(float4*)(out + (size_t)row * 1024 + c) = o;
}

// ---------------- launcher ----------------
// ws map (bytes), ws_size >= 86,507,520 proven:
//   [0,32)   cnt    [64,96) cnt2   [128,164) offs
//   [256,65792) topk_idx  [65792,131328) topk_w
//   [131328,200960) rowid [200960,270592) rowwt [270592,340224) rowslot
//   [524288, 36175872)  Hb  (ROWCAP*2048); shared phase uses rows 0..8191
//     (first 16 MB) -> sw1t/sw3t/sw2t stashed at Hb+16MB (6 MB, dead rows),
//     overwritten later by routed Hb AFTER shared k_out has consumed them.
//   [36175872, 69730304) WA..WB (32 MB): w1t/w3t images; later Yb
//   [69730304, 86507520) WC (16 MB): Xbf until routed k_h done, then w2t
extern "C" void kernel_launch(void* const* d_in, const int* in_sizes, int n_in,
                              void* d_out, int out_size, void* d_ws, size_t ws_size,
                              hipStream_t stream)
{
    const float* x   = (const float*)d_in[0];
    const float* gw  = (const float*)d_in[1];
    const float* w1  = (const float*)d_in[2];
    const float* b1  = (const float*)d_in[3];
    const float* w2  = (const float*)d_in[4];
    const float* b2  = (const float*)d_in[5];
    const float* w3  = (const float*)d_in[6];
    const float* b3  = (const float*)d_in[7];
    const float* sw1 = (const float*)d_in[8];
    const float* sb1 = (const float*)d_in[9];
    const float* sw2 = (const float*)d_in[10];
    const float* sb2 = (const float*)d_in[11];
    const float* sw3 = (const float*)d_in[12];
    const float* sb3 = (const float*)d_in[13];
    float* out = (float*)d_out;

    char* ws = (char*)d_ws;
    int*   cnt      = (int*)(ws);
    int*   cnt2     = (int*)(ws + 64);
    int*   offs     = (int*)(ws + 128);
    int*   topk_idx = (int*)(ws + 256);
    float* topk_w   = (float*)(ws + 256 + 65536);
    int*   rowid    = (int*)(ws + 256 + 131072);
    float* rowwt    = (float*)(ws + 256 + 131072 + ROWCAP * 4);
    int*   rowslot  = (int*)(ws + 256 + 131072 + ROWCAP * 8);
    ushort* Hb = (ushort*)(ws + 524288);
    ushort* WA = (ushort*)(ws + 524288 + (size_t)ROWCAP * 2048); // 36,175,872
    ushort* WB = WA + (8u << 20);                                // +16 MB
    ushort* WC = WB + (8u << 20);                                // +16 MB

    ushort* sw1t = Hb + (8u << 20);         // Hb tail: bytes [16M,18M) of Hb
    ushort* sw3t = sw1t + (1u << 20);       // [18M,20M)
    ushort* sw2t = sw3t + (1u << 20);       // [20M,22M)
    ushort* w1t  = WA;
    ushort* w3t  = WB;
    ushort* w2t  = WC;   // after Xbf dead
    ushort* Xbf  = WC;   // alive until routed k_h done
    ushort* Yb   = WA;   // 32 MB spanning WA+WB; w1t/w3t dead by routed k_out

    hipMemsetAsync(ws, 0, 256, stream);

    k_gate<<<256, 256, 0, stream>>>(x, gw, topk_idx, topk_w, cnt, Xbf);
    k_prefix<<<1, 64, 0, stream>>>(cnt, offs);
    k_scatter<<<32, 256, 0, stream>>>(topk_idx, topk_w, offs, cnt2, rowid, rowwt, rowslot);

    // all weight transposes except w2 (whose dst region still holds Xbf)
    k_tw<<<dim3(128, 19), 256, 0, stream>>>(w1, w1t, 8, w3, w3t, 8,
                                            sw1, sw1t, 1, sw3, sw3t, 1,
                                            sw2, sw2t);

    // shared expert
    k_h<false><<<dim3(16, 64), 256, 0, stream>>>(Xbf, sw1t, sb1, sw3t, sb3, Hb,
                                                 nullptr, nullptr, nullptr);
    k_out<0><<<dim3(16, 64), 256, 0, stream>>>(Hb, sw2t, sb2, out,
                                               nullptr, nullptr, nullptr, nullptr,
                                               nullptr, nullptr);

    // routed experts
    k_h<true><<<dim3(16, ROWCAP / 128), 256, 0, stream>>>(Xbf, w1t, b1, w3t, b3, Hb,
                                                          rowid, offs, cnt);
    k_tw<<<dim3(128, 8), 256, 0, stream>>>(w2, w2t, 8, nullptr, nullptr, 0,
                                           nullptr, nullptr, 0, nullptr, nullptr, 0,
                                           nullptr, nullptr);   // overwrites Xbf (dead)
    k_out<2><<<dim3(16, ROWCAP / 128), 256, 0, stream>>>(Hb, w2t, b2, out,
                                                         rowid, offs, cnt, rowwt,
                                                         rowslot, Yb);
    k_combine<<<T_TOK, 256, 0, stream>>>(out, Yb);
}